// Round 1
// baseline (579.455 us; speedup 1.0000x reference)
//
#include <hip/hip_runtime.h>
#include <stdint.h>
#include <math.h>

typedef __bf16 bf16_t;
typedef __bf16 bf16x8 __attribute__((ext_vector_type(8)));
typedef float f32x4 __attribute__((ext_vector_type(4)));

#define B_ 4
#define L_ 2048
#define D_ 1024
#define H_ 16
#define DH_ 64
#define M_ (B_ * L_)   // 8192

__device__ __forceinline__ void gload16(const bf16_t* gsrc, bf16_t* ldst) {
    __builtin_amdgcn_global_load_lds(
        (__attribute__((address_space(1))) void*)(void*)(gsrc),
        (__attribute__((address_space(3))) void*)(ldst), 16, 0, 0);
}

__device__ __forceinline__ float gelu_exact(float v) {
    return 0.5f * v * (1.0f + erff(v * 0.70710678118654752f));
}

// ---------------- weight transpose fp32 -> bf16, WT[n][k] = W[k][n] ----------------
__global__ __launch_bounds__(256) void transpose_bf16(const float* __restrict__ W,
                                                      bf16_t* __restrict__ WT) {
    __shared__ float tile[32][33];
    const int x = threadIdx.x, y0 = threadIdx.y;
    const int bx = blockIdx.x * 32, by = blockIdx.y * 32;
    for (int kk = 0; kk < 4; ++kk)
        tile[y0 + kk * 8][x] = W[(size_t)(by + y0 + kk * 8) * D_ + bx + x];
    __syncthreads();
    for (int kk = 0; kk < 4; ++kk)
        WT[(size_t)(bx + y0 + kk * 8) * D_ + by + x] = (bf16_t)tile[x][y0 + kk * 8];
}

// ---------------- LayerNorm 1: x -> h (bf16) ----------------
__global__ __launch_bounds__(256) void ln1_kernel(const float* __restrict__ x,
                                                  const float* __restrict__ g,
                                                  const float* __restrict__ b,
                                                  bf16_t* __restrict__ h) {
    const int row = blockIdx.x, t = threadIdx.x;
    const float4 v = *(const float4*)(x + (size_t)row * D_ + t * 4);
    float s = v.x + v.y + v.z + v.w;
    float s2 = v.x * v.x + v.y * v.y + v.z * v.z + v.w * v.w;
    for (int m = 1; m < 64; m <<= 1) { s += __shfl_xor(s, m, 64); s2 += __shfl_xor(s2, m, 64); }
    __shared__ float red[2][4];
    if ((t & 63) == 0) { red[0][t >> 6] = s; red[1][t >> 6] = s2; }
    __syncthreads();
    s = red[0][0] + red[0][1] + red[0][2] + red[0][3];
    s2 = red[1][0] + red[1][1] + red[1][2] + red[1][3];
    const float mean = s * (1.f / 1024.f);
    const float var = s2 * (1.f / 1024.f) - mean * mean;
    const float rstd = rsqrtf(var + 1e-6f);
    const float4 gv = *(const float4*)(g + t * 4);
    const float4 bv = *(const float4*)(b + t * 4);
    union { bf16_t h4[4]; uint2 u; } o;
    o.h4[0] = (bf16_t)((v.x - mean) * rstd * gv.x + bv.x);
    o.h4[1] = (bf16_t)((v.y - mean) * rstd * gv.y + bv.y);
    o.h4[2] = (bf16_t)((v.z - mean) * rstd * gv.z + bv.z);
    o.h4[3] = (bf16_t)((v.w - mean) * rstd * gv.w + bv.w);
    *(uint2*)(h + (size_t)row * D_ + t * 4) = o.u;
}

// ---------------- residual add + LayerNorm 2 ----------------
__global__ __launch_bounds__(256) void add_ln2_kernel(const float* __restrict__ x,
                                                      const float* __restrict__ attn,
                                                      const float* __restrict__ g,
                                                      const float* __restrict__ b,
                                                      float* __restrict__ resid,
                                                      bf16_t* __restrict__ h) {
    const int row = blockIdx.x, t = threadIdx.x;
    const float4 xv = *(const float4*)(x + (size_t)row * D_ + t * 4);
    const float4 av = *(const float4*)(attn + (size_t)row * D_ + t * 4);
    float4 v;
    v.x = xv.x + av.x; v.y = xv.y + av.y; v.z = xv.z + av.z; v.w = xv.w + av.w;
    *(float4*)(resid + (size_t)row * D_ + t * 4) = v;
    float s = v.x + v.y + v.z + v.w;
    float s2 = v.x * v.x + v.y * v.y + v.z * v.z + v.w * v.w;
    for (int m = 1; m < 64; m <<= 1) { s += __shfl_xor(s, m, 64); s2 += __shfl_xor(s2, m, 64); }
    __shared__ float red[2][4];
    if ((t & 63) == 0) { red[0][t >> 6] = s; red[1][t >> 6] = s2; }
    __syncthreads();
    s = red[0][0] + red[0][1] + red[0][2] + red[0][3];
    s2 = red[1][0] + red[1][1] + red[1][2] + red[1][3];
    const float mean = s * (1.f / 1024.f);
    const float var = s2 * (1.f / 1024.f) - mean * mean;
    const float rstd = rsqrtf(var + 1e-6f);
    const float4 gv = *(const float4*)(g + t * 4);
    const float4 bv = *(const float4*)(b + t * 4);
    union { bf16_t h4[4]; uint2 u; } o;
    o.h4[0] = (bf16_t)((v.x - mean) * rstd * gv.x + bv.x);
    o.h4[1] = (bf16_t)((v.y - mean) * rstd * gv.y + bv.y);
    o.h4[2] = (bf16_t)((v.z - mean) * rstd * gv.z + bv.z);
    o.h4[3] = (bf16_t)((v.w - mean) * rstd * gv.w + bv.w);
    *(uint2*)(h + (size_t)row * D_ + t * 4) = o.u;
}

// ---------------- m97-style GEMM: C[M,N] = A[M,K] @ BT[N,K]^T + bias ----------------
// MODE 0: bf16 out (QKV). MODE 1: exact GELU, bf16 out. MODE 2: +resid, fp32 out.
template <int MODE>
__global__ __launch_bounds__(256) void gemm_bt(const bf16_t* __restrict__ A,
                                               const bf16_t* __restrict__ BT,
                                               const float* __restrict__ bias,
                                               const float* __restrict__ resid,
                                               bf16_t* __restrict__ outb,
                                               float* __restrict__ outf) {
    constexpr int K = 1024, N = 1024;
    __shared__ bf16_t As[128 * 32];
    __shared__ bf16_t Bs[128 * 32];
    const int t = threadIdx.x;
    const int wave = t >> 6, lane = t & 63;
    const int l16 = lane & 15, g4 = lane >> 4;
    const int bm = blockIdx.x * 128, bn = blockIdx.y * 128;
    const int wm = (wave >> 1) * 64, wn = (wave & 1) * 64;

    f32x4 acc[4][4];
    for (int i = 0; i < 4; ++i)
        for (int j = 0; j < 4; ++j) acc[i][j] = (f32x4){0.f, 0.f, 0.f, 0.f};

    const int ar = t >> 2, ak = (t & 3) * 8;
    const bf16_t* Ag = A + (size_t)(bm + ar) * K + ak;
    const bf16_t* Bg = BT + (size_t)(bn + ar) * K + ak;
    bf16_t* Al = As + t * 8;
    bf16_t* Bl = Bs + t * 8;

    for (int kk = 0; kk < K; kk += 32) {
        __syncthreads();
        gload16(Ag + kk, Al);
        gload16(Ag + (size_t)64 * K + kk, Al + 2048);
        gload16(Bg + kk, Bl);
        gload16(Bg + (size_t)64 * K + kk, Bl + 2048);
        __syncthreads();
        bf16x8 af[4], bfr[4];
        for (int i = 0; i < 4; ++i)
            af[i] = *(const bf16x8*)&As[(wm + i * 16 + l16) * 32 + g4 * 8];
        for (int j = 0; j < 4; ++j)
            bfr[j] = *(const bf16x8*)&Bs[(wn + j * 16 + l16) * 32 + g4 * 8];
        for (int i = 0; i < 4; ++i)
            for (int j = 0; j < 4; ++j)
                acc[i][j] = __builtin_amdgcn_mfma_f32_16x16x32_bf16(af[i], bfr[j], acc[i][j], 0, 0, 0);
    }

    for (int i = 0; i < 4; ++i)
        for (int j = 0; j < 4; ++j) {
            const int col = bn + wn + j * 16 + l16;
            const float bv = bias[col];
            const int row0 = bm + wm + i * 16 + g4 * 4;
            for (int r = 0; r < 4; ++r) {
                float vv = acc[i][j][r] + bv;
                const size_t idx = (size_t)(row0 + r) * N + col;
                if (MODE == 0) {
                    outb[idx] = (bf16_t)vv;
                } else if (MODE == 1) {
                    outb[idx] = (bf16_t)gelu_exact(vv);
                } else {
                    outf[idx] = vv + resid[idx];
                }
            }
        }
}

// ---------------- flash attention: one block per (q-tile of 128, b*H+h) ----------------
__global__ __launch_bounds__(256) void attn_kernel(const bf16_t* __restrict__ q,
                                                   const bf16_t* __restrict__ k,
                                                   const bf16_t* __restrict__ v,
                                                   const int* __restrict__ mask,
                                                   float* __restrict__ attn) {
    __shared__ bf16_t Ks[128 * 72];    // [key][d], stride 72 (144B, 16B-aligned, 2-way banks)
    __shared__ bf16_t VTs[64 * 136];   // [d][key], stride 136
    __shared__ bf16_t Ps[128 * 72];    // [q][key-halftile], stride 72

    const int t = threadIdx.x;
    const int wave = t >> 6, lane = t & 63;
    const int l16 = lane & 15, g4 = lane >> 4;
    const int bh = blockIdx.y;
    const int b = bh >> 4, h = bh & 15;
    const int q0 = blockIdx.x * 128;
    const int qrow_w = q0 + wave * 32;

    bf16x8 qf[2][2];
    for (int ti = 0; ti < 2; ++ti)
        for (int c = 0; c < 2; ++c)
            qf[ti][c] = *(const bf16x8*)(q + (size_t)(b * L_ + qrow_w + ti * 16 + l16) * D_ +
                                         h * DH_ + c * 32 + g4 * 8);

    f32x4 accO[2][4];
    float mst[2][4], lst[2][4];
    for (int ti = 0; ti < 2; ++ti)
        for (int j = 0; j < 4; ++j) {
            accO[ti][j] = (f32x4){0.f, 0.f, 0.f, 0.f};
            mst[ti][j] = -3.0e38f;
            lst[ti][j] = 0.f;
        }

    for (int k0 = 0; k0 < L_; k0 += 128) {
        __syncthreads();
        // stage K [128][64] row-major (padded)
        for (int cc = 0; cc < 4; ++cc) {
            const int c = t + cc * 256;
            const int row = c >> 3, off = (c & 7) * 8;
            *(uint4*)&Ks[row * 72 + off] =
                *(const uint4*)(k + (size_t)(b * L_ + k0 + row) * D_ + h * DH_ + off);
        }
        // stage V transposed -> VTs[d][key]
        for (int cc = 0; cc < 4; ++cc) {
            const int c = t + cc * 256;
            const int krel = c >> 3, d0 = (c & 7) * 8;
            union { uint4 u; bf16_t e[8]; } tv;
            tv.u = *(const uint4*)(v + (size_t)(b * L_ + k0 + krel) * D_ + h * DH_ + d0);
            for (int j = 0; j < 8; ++j) VTs[(d0 + j) * 136 + krel] = tv.e[j];
        }
        __syncthreads();

        // S = Q K^T  (per wave: 32 q-rows x 128 keys)
        f32x4 s[2][8];
        for (int tj = 0; tj < 8; ++tj) {
            const bf16x8 kf0 = *(const bf16x8*)&Ks[(tj * 16 + l16) * 72 + g4 * 8];
            const bf16x8 kf1 = *(const bf16x8*)&Ks[(tj * 16 + l16) * 72 + 32 + g4 * 8];
            for (int ti = 0; ti < 2; ++ti) {
                f32x4 a = (f32x4){0.f, 0.f, 0.f, 0.f};
                a = __builtin_amdgcn_mfma_f32_16x16x32_bf16(qf[ti][0], kf0, a, 0, 0, 0);
                a = __builtin_amdgcn_mfma_f32_16x16x32_bf16(qf[ti][1], kf1, a, 0, 0, 0);
                s[ti][tj] = a;
            }
        }

        bool mok[8];
        for (int tj = 0; tj < 8; ++tj) mok[tj] = (mask[b * L_ + k0 + tj * 16 + l16] != 0);

        // online softmax (C-layout: col = l16, row = g4*4 + r)
        for (int ti = 0; ti < 2; ++ti)
            for (int r = 0; r < 4; ++r) {
                float sv[8];
                float tmax = -3.0e38f;
                for (int tj = 0; tj < 8; ++tj) {
                    float x2 = s[ti][tj][r] * 0.125f;
                    x2 = mok[tj] ? x2 : -1.0e30f;
                    sv[tj] = x2;
                    tmax = fmaxf(tmax, x2);
                }
                tmax = fmaxf(tmax, __shfl_xor(tmax, 1, 64));
                tmax = fmaxf(tmax, __shfl_xor(tmax, 2, 64));
                tmax = fmaxf(tmax, __shfl_xor(tmax, 4, 64));
                tmax = fmaxf(tmax, __shfl_xor(tmax, 8, 64));
                const float mnew = fmaxf(mst[ti][r], tmax);
                const float alpha = __expf(mst[ti][r] - mnew);
                float rsum = 0.f;
                for (int tj = 0; tj < 8; ++tj) {
                    const float p = __expf(sv[tj] - mnew);
                    s[ti][tj][r] = p;
                    rsum += p;
                }
                rsum += __shfl_xor(rsum, 1, 64);
                rsum += __shfl_xor(rsum, 2, 64);
                rsum += __shfl_xor(rsum, 4, 64);
                rsum += __shfl_xor(rsum, 8, 64);
                lst[ti][r] = lst[ti][r] * alpha + rsum;
                mst[ti][r] = mnew;
                for (int j = 0; j < 4; ++j) accO[ti][j][r] *= alpha;
            }

        // P through LDS (A-layout round trip), 64 keys per pass; rows are wave-private
        for (int p = 0; p < 2; ++p) {
            for (int ti = 0; ti < 2; ++ti)
                for (int tj = 0; tj < 4; ++tj)
                    for (int r = 0; r < 4; ++r)
                        Ps[(wave * 32 + ti * 16 + g4 * 4 + r) * 72 + tj * 16 + l16] =
                            (bf16_t)s[ti][p * 4 + tj][r];
            for (int ti = 0; ti < 2; ++ti)
                for (int c = 0; c < 2; ++c) {
                    const bf16x8 pf =
                        *(const bf16x8*)&Ps[(wave * 32 + ti * 16 + l16) * 72 + c * 32 + g4 * 8];
                    for (int j = 0; j < 4; ++j) {
                        const bf16x8 vf =
                            *(const bf16x8*)&VTs[(j * 16 + l16) * 136 + p * 64 + c * 32 + g4 * 8];
                        accO[ti][j] = __builtin_amdgcn_mfma_f32_16x16x32_bf16(pf, vf, accO[ti][j], 0, 0, 0);
                    }
                }
        }
    }

    for (int ti = 0; ti < 2; ++ti)
        for (int j = 0; j < 4; ++j)
            for (int r = 0; r < 4; ++r) {
                const int row = q0 + wave * 32 + ti * 16 + g4 * 4 + r;
                attn[(size_t)(b * L_ + row) * D_ + h * DH_ + j * 16 + l16] =
                    accO[ti][j][r] / lst[ti][r];
            }
}

extern "C" void kernel_launch(void* const* d_in, const int* in_sizes, int n_in,
                              void* d_out, int out_size, void* d_ws, size_t ws_size,
                              hipStream_t stream) {
    const float* x    = (const float*)d_in[0];
    const int*   mask = (const int*)d_in[1];
    const float* Wq   = (const float*)d_in[2];
    const float* bq   = (const float*)d_in[3];
    const float* Wk   = (const float*)d_in[4];
    const float* bk   = (const float*)d_in[5];
    const float* Wv   = (const float*)d_in[6];
    const float* bv   = (const float*)d_in[7];
    const float* g1   = (const float*)d_in[8];
    const float* b1   = (const float*)d_in[9];
    const float* g2   = (const float*)d_in[10];
    const float* b2   = (const float*)d_in[11];
    const float* Wo1  = (const float*)d_in[12];
    const float* bo1  = (const float*)d_in[13];
    const float* Wo2  = (const float*)d_in[14];
    const float* bo2  = (const float*)d_in[15];

    char* ws = (char*)d_ws;
    const size_t MBs = 1ull << 20;
    bf16_t* WqT  = (bf16_t*)(ws + 0 * MBs);
    bf16_t* WkT  = (bf16_t*)(ws + 2 * MBs);
    bf16_t* WvT  = (bf16_t*)(ws + 4 * MBs);
    bf16_t* Wo1T = (bf16_t*)(ws + 6 * MBs);
    bf16_t* Wo2T = (bf16_t*)(ws + 8 * MBs);
    bf16_t* h1   = (bf16_t*)(ws + 10 * MBs);
    bf16_t* qb   = (bf16_t*)(ws + 26 * MBs);
    bf16_t* kb   = (bf16_t*)(ws + 42 * MBs);
    bf16_t* vb   = (bf16_t*)(ws + 58 * MBs);
    float*  attn = (float*)(ws + 74 * MBs);
    float*  resid= (float*)(ws + 106 * MBs);
    bf16_t* h2   = qb;   // reuse: q no longer needed after attention
    bf16_t* gact = kb;   // reuse: k no longer needed after attention

    const dim3 tb(32, 8), tg(32, 32);
    transpose_bf16<<<tg, tb, 0, stream>>>(Wq, WqT);
    transpose_bf16<<<tg, tb, 0, stream>>>(Wk, WkT);
    transpose_bf16<<<tg, tb, 0, stream>>>(Wv, WvT);
    transpose_bf16<<<tg, tb, 0, stream>>>(Wo1, Wo1T);
    transpose_bf16<<<tg, tb, 0, stream>>>(Wo2, Wo2T);

    ln1_kernel<<<M_, 256, 0, stream>>>(x, g1, b1, h1);

    const dim3 gg(M_ / 128, D_ / 128);
    gemm_bt<0><<<gg, 256, 0, stream>>>(h1, WqT, bq, nullptr, qb, nullptr);
    gemm_bt<0><<<gg, 256, 0, stream>>>(h1, WkT, bk, nullptr, kb, nullptr);
    gemm_bt<0><<<gg, 256, 0, stream>>>(h1, WvT, bv, nullptr, vb, nullptr);

    attn_kernel<<<dim3(L_ / 128, B_ * H_), 256, 0, stream>>>(qb, kb, vb, mask, attn);

    add_ln2_kernel<<<M_, 256, 0, stream>>>(x, attn, g2, b2, resid, h2);

    gemm_bt<1><<<gg, 256, 0, stream>>>(h2, Wo1T, bo1, nullptr, gact, nullptr);
    gemm_bt<2><<<gg, 256, 0, stream>>>(gact, Wo2T, bo2, resid, nullptr, (float*)d_out);
}

// Round 2
// 489.159 us; speedup vs baseline: 1.1846x; 1.1846x over previous
//
#include <hip/hip_runtime.h>
#include <stdint.h>
#include <math.h>

typedef __bf16 bf16_t;
typedef __bf16 bf16x8 __attribute__((ext_vector_type(8)));
typedef __bf16 bf16x4 __attribute__((ext_vector_type(4)));
typedef short short4v __attribute__((ext_vector_type(4)));
typedef float f32x4 __attribute__((ext_vector_type(4)));

#define B_ 4
#define L_ 2048
#define D_ 1024
#define H_ 16
#define DH_ 64
#define M_ (B_ * L_)   // 8192
#define LOG2E 1.4426950408889634f

__device__ __forceinline__ void gload16(const bf16_t* gsrc, bf16_t* ldst) {
    __builtin_amdgcn_global_load_lds(
        (__attribute__((address_space(1))) void*)(void*)(gsrc),
        (__attribute__((address_space(3))) void*)(ldst), 16, 0, 0);
}

__device__ __forceinline__ float gelu_exact(float v) {
    return 0.5f * v * (1.0f + erff(v * 0.70710678118654752f));
}

__device__ __forceinline__ float fast_exp2(float x) {
#if __has_builtin(__builtin_amdgcn_exp2f)
    return __builtin_amdgcn_exp2f(x);
#else
    return exp2f(x);
#endif
}

__device__ __forceinline__ f32x4 mfma16(bf16x4 a, bf16x4 b, f32x4 c) {
#if __has_builtin(__builtin_amdgcn_mfma_f32_16x16x16_bf16)
    return __builtin_amdgcn_mfma_f32_16x16x16_bf16(a, b, c, 0, 0, 0);
#else
    union U { bf16x4 h; short4v s; };
    U ua, ub; ua.h = a; ub.h = b;
    return __builtin_amdgcn_mfma_f32_16x16x16bf16_1k(ua.s, ub.s, c, 0, 0, 0);
#endif
}

// ---------------- weight transpose fp32 -> bf16, WT[n][k] = W[k][n] ----------------
__global__ __launch_bounds__(256) void transpose_bf16(const float* __restrict__ W,
                                                      bf16_t* __restrict__ WT) {
    __shared__ float tile[32][33];
    const int x = threadIdx.x, y0 = threadIdx.y;
    const int bx = blockIdx.x * 32, by = blockIdx.y * 32;
    for (int kk = 0; kk < 4; ++kk)
        tile[y0 + kk * 8][x] = W[(size_t)(by + y0 + kk * 8) * D_ + bx + x];
    __syncthreads();
    for (int kk = 0; kk < 4; ++kk)
        WT[(size_t)(bx + y0 + kk * 8) * D_ + by + x] = (bf16_t)tile[x][y0 + kk * 8];
}

// ---------------- LayerNorm 1: x -> h (bf16) ----------------
__global__ __launch_bounds__(256) void ln1_kernel(const float* __restrict__ x,
                                                  const float* __restrict__ g,
                                                  const float* __restrict__ b,
                                                  bf16_t* __restrict__ h) {
    const int row = blockIdx.x, t = threadIdx.x;
    const float4 v = *(const float4*)(x + (size_t)row * D_ + t * 4);
    float s = v.x + v.y + v.z + v.w;
    float s2 = v.x * v.x + v.y * v.y + v.z * v.z + v.w * v.w;
    for (int m = 1; m < 64; m <<= 1) { s += __shfl_xor(s, m, 64); s2 += __shfl_xor(s2, m, 64); }
    __shared__ float red[2][4];
    if ((t & 63) == 0) { red[0][t >> 6] = s; red[1][t >> 6] = s2; }
    __syncthreads();
    s = red[0][0] + red[0][1] + red[0][2] + red[0][3];
    s2 = red[1][0] + red[1][1] + red[1][2] + red[1][3];
    const float mean = s * (1.f / 1024.f);
    const float var = s2 * (1.f / 1024.f) - mean * mean;
    const float rstd = rsqrtf(var + 1e-6f);
    const float4 gv = *(const float4*)(g + t * 4);
    const float4 bv = *(const float4*)(b + t * 4);
    union { bf16_t h4[4]; uint2 u; } o;
    o.h4[0] = (bf16_t)((v.x - mean) * rstd * gv.x + bv.x);
    o.h4[1] = (bf16_t)((v.y - mean) * rstd * gv.y + bv.y);
    o.h4[2] = (bf16_t)((v.z - mean) * rstd * gv.z + bv.z);
    o.h4[3] = (bf16_t)((v.w - mean) * rstd * gv.w + bv.w);
    *(uint2*)(h + (size_t)row * D_ + t * 4) = o.u;
}

// ---------------- residual add + LayerNorm 2 ----------------
__global__ __launch_bounds__(256) void add_ln2_kernel(const float* __restrict__ x,
                                                      const float* __restrict__ attn,
                                                      const float* __restrict__ g,
                                                      const float* __restrict__ b,
                                                      float* __restrict__ resid,
                                                      bf16_t* __restrict__ h) {
    const int row = blockIdx.x, t = threadIdx.x;
    const float4 xv = *(const float4*)(x + (size_t)row * D_ + t * 4);
    const float4 av = *(const float4*)(attn + (size_t)row * D_ + t * 4);
    float4 v;
    v.x = xv.x + av.x; v.y = xv.y + av.y; v.z = xv.z + av.z; v.w = xv.w + av.w;
    *(float4*)(resid + (size_t)row * D_ + t * 4) = v;
    float s = v.x + v.y + v.z + v.w;
    float s2 = v.x * v.x + v.y * v.y + v.z * v.z + v.w * v.w;
    for (int m = 1; m < 64; m <<= 1) { s += __shfl_xor(s, m, 64); s2 += __shfl_xor(s2, m, 64); }
    __shared__ float red[2][4];
    if ((t & 63) == 0) { red[0][t >> 6] = s; red[1][t >> 6] = s2; }
    __syncthreads();
    s = red[0][0] + red[0][1] + red[0][2] + red[0][3];
    s2 = red[1][0] + red[1][1] + red[1][2] + red[1][3];
    const float mean = s * (1.f / 1024.f);
    const float var = s2 * (1.f / 1024.f) - mean * mean;
    const float rstd = rsqrtf(var + 1e-6f);
    const float4 gv = *(const float4*)(g + t * 4);
    const float4 bv = *(const float4*)(b + t * 4);
    union { bf16_t h4[4]; uint2 u; } o;
    o.h4[0] = (bf16_t)((v.x - mean) * rstd * gv.x + bv.x);
    o.h4[1] = (bf16_t)((v.y - mean) * rstd * gv.y + bv.y);
    o.h4[2] = (bf16_t)((v.z - mean) * rstd * gv.z + bv.z);
    o.h4[3] = (bf16_t)((v.w - mean) * rstd * gv.w + bv.w);
    *(uint2*)(h + (size_t)row * D_ + t * 4) = o.u;
}

// ---------------- fused QKV GEMM: [8192,1024] x [3072,1024]^T, q scaled 0.125 ----------------
__global__ __launch_bounds__(256) void gemm_qkv(const bf16_t* __restrict__ A,
                                                const bf16_t* __restrict__ BT,
                                                const float* __restrict__ bq,
                                                const float* __restrict__ bk,
                                                const float* __restrict__ bv,
                                                bf16_t* __restrict__ qb,
                                                bf16_t* __restrict__ kb,
                                                bf16_t* __restrict__ vb) {
    constexpr int K = 1024;
    __shared__ bf16_t As[128 * 32];
    __shared__ bf16_t Bs[128 * 32];
    const int t = threadIdx.x;
    const int wave = t >> 6, lane = t & 63;
    const int l16 = lane & 15, g4 = lane >> 4;
    const int bm = blockIdx.x * 128, bn = blockIdx.y * 128;
    const int wm = (wave >> 1) * 64, wn = (wave & 1) * 64;

    f32x4 acc[4][4];
    for (int i = 0; i < 4; ++i)
        for (int j = 0; j < 4; ++j) acc[i][j] = (f32x4){0.f, 0.f, 0.f, 0.f};

    const int ar = t >> 2, ak = (t & 3) * 8;
    const bf16_t* Ag = A + (size_t)(bm + ar) * K + ak;
    const bf16_t* Bg = BT + (size_t)(bn + ar) * K + ak;
    bf16_t* Al = As + t * 8;
    bf16_t* Bl = Bs + t * 8;

    for (int kk = 0; kk < K; kk += 32) {
        __syncthreads();
        gload16(Ag + kk, Al);
        gload16(Ag + (size_t)64 * K + kk, Al + 2048);
        gload16(Bg + kk, Bl);
        gload16(Bg + (size_t)64 * K + kk, Bl + 2048);
        __syncthreads();
        bf16x8 af[4], bfr[4];
        for (int i = 0; i < 4; ++i)
            af[i] = *(const bf16x8*)&As[(wm + i * 16 + l16) * 32 + g4 * 8];
        for (int j = 0; j < 4; ++j)
            bfr[j] = *(const bf16x8*)&Bs[(wn + j * 16 + l16) * 32 + g4 * 8];
        for (int i = 0; i < 4; ++i)
            for (int j = 0; j < 4; ++j)
                acc[i][j] = __builtin_amdgcn_mfma_f32_16x16x32_bf16(af[i], bfr[j], acc[i][j], 0, 0, 0);
    }

    const int which = bn >> 10;             // 0=q, 1=k, 2=v (uniform per block)
    const int c0 = bn & 1023;
    const float* bias = (which == 0) ? bq : (which == 1) ? bk : bv;
    bf16_t* ob = (which == 0) ? qb : (which == 1) ? kb : vb;
    const float scale = (which == 0) ? 0.125f : 1.0f;

    for (int i = 0; i < 4; ++i)
        for (int j = 0; j < 4; ++j) {
            const int col = c0 + wn + j * 16 + l16;
            const float bvv = bias[col];
            const int row0 = bm + wm + i * 16 + g4 * 4;
            for (int r = 0; r < 4; ++r) {
                const float vv = (acc[i][j][r] + bvv) * scale;
                ob[(size_t)(row0 + r) * D_ + col] = (bf16_t)vv;
            }
        }
}

// ---------------- GEMM: C[M,1024] = A @ BT^T + bias; MODE 1 gelu->bf16, MODE 2 +resid->f32 ----
template <int MODE>
__global__ __launch_bounds__(256) void gemm_bt(const bf16_t* __restrict__ A,
                                               const bf16_t* __restrict__ BT,
                                               const float* __restrict__ bias,
                                               const float* __restrict__ resid,
                                               bf16_t* __restrict__ outb,
                                               float* __restrict__ outf) {
    constexpr int K = 1024, N = 1024;
    __shared__ bf16_t As[128 * 32];
    __shared__ bf16_t Bs[128 * 32];
    const int t = threadIdx.x;
    const int wave = t >> 6, lane = t & 63;
    const int l16 = lane & 15, g4 = lane >> 4;
    const int bm = blockIdx.x * 128, bn = blockIdx.y * 128;
    const int wm = (wave >> 1) * 64, wn = (wave & 1) * 64;

    f32x4 acc[4][4];
    for (int i = 0; i < 4; ++i)
        for (int j = 0; j < 4; ++j) acc[i][j] = (f32x4){0.f, 0.f, 0.f, 0.f};

    const int ar = t >> 2, ak = (t & 3) * 8;
    const bf16_t* Ag = A + (size_t)(bm + ar) * K + ak;
    const bf16_t* Bg = BT + (size_t)(bn + ar) * K + ak;
    bf16_t* Al = As + t * 8;
    bf16_t* Bl = Bs + t * 8;

    for (int kk = 0; kk < K; kk += 32) {
        __syncthreads();
        gload16(Ag + kk, Al);
        gload16(Ag + (size_t)64 * K + kk, Al + 2048);
        gload16(Bg + kk, Bl);
        gload16(Bg + (size_t)64 * K + kk, Bl + 2048);
        __syncthreads();
        bf16x8 af[4], bfr[4];
        for (int i = 0; i < 4; ++i)
            af[i] = *(const bf16x8*)&As[(wm + i * 16 + l16) * 32 + g4 * 8];
        for (int j = 0; j < 4; ++j)
            bfr[j] = *(const bf16x8*)&Bs[(wn + j * 16 + l16) * 32 + g4 * 8];
        for (int i = 0; i < 4; ++i)
            for (int j = 0; j < 4; ++j)
                acc[i][j] = __builtin_amdgcn_mfma_f32_16x16x32_bf16(af[i], bfr[j], acc[i][j], 0, 0, 0);
    }

    for (int i = 0; i < 4; ++i)
        for (int j = 0; j < 4; ++j) {
            const int col = bn + wn + j * 16 + l16;
            const float bv = bias[col];
            const int row0 = bm + wm + i * 16 + g4 * 4;
            for (int r = 0; r < 4; ++r) {
                float vv = acc[i][j][r] + bv;
                const size_t idx = (size_t)(row0 + r) * N + col;
                if (MODE == 1) {
                    outb[idx] = (bf16_t)gelu_exact(vv);
                } else {
                    outf[idx] = vv + resid[idx];
                }
            }
        }
}

// ---------------- flash attention v2: S^T trick, no P round-trip ----------------
// grid (16, 64); block 256. q pre-scaled by 0.125 in gemm_qkv.
#define KS_STRIDE 72
#define VT_STRIDE 152
#define OS_STRIDE 72
__global__ __launch_bounds__(256, 3) void attn_kernel(const bf16_t* __restrict__ q,
                                                      const bf16_t* __restrict__ k,
                                                      const bf16_t* __restrict__ v,
                                                      const int* __restrict__ mask,
                                                      float* __restrict__ attn) {
    __shared__ char smem[18432 + 19456];
    bf16_t* Ks = (bf16_t*)smem;                  // [128][72]
    bf16_t* VT = (bf16_t*)(smem + 18432);        // [64][152]  (V^T: d x key)
    float*  Os = (float*)smem;                   // epilogue overlay [64][72]

    const int t = threadIdx.x;
    const int wave = t >> 6, lane = t & 63;
    const int l16 = lane & 15, g4 = lane >> 4;
    const int bh = blockIdx.y;
    const int b = bh >> 4, h = bh & 15;
    const int q0 = blockIdx.x * 128;

    // Q fragments (B-operand): lane n=q(l16), holds d = c*32 + g4*8 + j
    bf16x8 qf[2][2];
    for (int ti = 0; ti < 2; ++ti)
        for (int c = 0; c < 2; ++c)
            qf[ti][c] = *(const bf16x8*)(q + (size_t)(b * L_ + q0 + wave * 32 + ti * 16 + l16) * D_ +
                                         h * DH_ + c * 32 + g4 * 8);

    f32x4 accO[2][4];   // O^T: col=l16=q, row=g4*4+r = d within dtile
    float mrow[2], lrow[2];
    for (int ti = 0; ti < 2; ++ti) {
        mrow[ti] = -3.0e38f; lrow[ti] = 0.f;
        for (int dt = 0; dt < 4; ++dt) accO[ti][dt] = (f32x4){0.f, 0.f, 0.f, 0.f};
    }
    bf16x4 pb[2][8];

    for (int k0 = 0; k0 < L_; k0 += 128) {
        __syncthreads();
        // stage K [128][64] row-major pad 72, vector 16B writes (conflict-free)
        for (int cc = 0; cc < 4; ++cc) {
            const int c = t + cc * 256;
            const int row = c >> 3, off = (c & 7) * 8;
            *(uint4*)&Ks[row * KS_STRIDE + off] =
                *(const uint4*)(k + (size_t)(b * L_ + k0 + row) * D_ + h * DH_ + off);
        }
        // stage V^T [64][128]: scalar global reads (lane=d -> 128B coalesced), 16B LDS writes
        {
            const int d = t & 63, kg = t >> 6;
            for (int k8 = 0; k8 < 4; ++k8) {
                union { uint4 u; bf16_t e[8]; } tv;
                #pragma unroll
                for (int i = 0; i < 8; ++i)
                    tv.e[i] = v[(size_t)(b * L_ + k0 + kg * 32 + k8 * 8 + i) * D_ + h * DH_ + d];
                *(uint4*)&VT[d * VT_STRIDE + kg * 32 + k8 * 8] = tv.u;
            }
        }
        __syncthreads();

        for (int ti = 0; ti < 2; ++ti) {
            // S^T = mfma(K_frag(rows=key), Q_frag(cols=q)): col=l16=q, row=g4*4+r=key
            f32x4 s[8];
            #pragma unroll
            for (int tj = 0; tj < 8; ++tj) {
                const bf16x8 kf0 = *(const bf16x8*)&Ks[(tj * 16 + l16) * KS_STRIDE + g4 * 8];
                const bf16x8 kf1 = *(const bf16x8*)&Ks[(tj * 16 + l16) * KS_STRIDE + 32 + g4 * 8];
                f32x4 a = (f32x4){0.f, 0.f, 0.f, 0.f};
                a = __builtin_amdgcn_mfma_f32_16x16x32_bf16(kf0, qf[ti][0], a, 0, 0, 0);
                a = __builtin_amdgcn_mfma_f32_16x16x32_bf16(kf1, qf[ti][1], a, 0, 0, 0);
                s[tj] = a;
            }
            // mask (additive -1e30), keys = k0 + tj*16 + g4*4 + r
            #pragma unroll
            for (int tj = 0; tj < 8; ++tj) {
                const int4 mv = *(const int4*)&mask[b * L_ + k0 + tj * 16 + g4 * 4];
                s[tj][0] += mv.x ? 0.f : -1.0e30f;
                s[tj][1] += mv.y ? 0.f : -1.0e30f;
                s[tj][2] += mv.z ? 0.f : -1.0e30f;
                s[tj][3] += mv.w ? 0.f : -1.0e30f;
            }
            // row max over this lane's 32 keys, then across g4 groups
            float tmax = -3.0e38f;
            #pragma unroll
            for (int tj = 0; tj < 8; ++tj)
                #pragma unroll
                for (int r = 0; r < 4; ++r) tmax = fmaxf(tmax, s[tj][r]);
            tmax = fmaxf(tmax, __shfl_xor(tmax, 16, 64));
            tmax = fmaxf(tmax, __shfl_xor(tmax, 32, 64));
            const float mnew = fmaxf(mrow[ti], tmax);
            const float alpha = fast_exp2((mrow[ti] - mnew) * LOG2E);
            const float cterm = -mnew * LOG2E;
            float rsum = 0.f;
            #pragma unroll
            for (int tj = 0; tj < 8; ++tj)
                #pragma unroll
                for (int r = 0; r < 4; ++r) {
                    const float p = fast_exp2(fmaf(s[tj][r], LOG2E, cterm));
                    s[tj][r] = p;
                    rsum += p;
                }
            rsum += __shfl_xor(rsum, 16, 64);
            rsum += __shfl_xor(rsum, 32, 64);
            lrow[ti] = lrow[ti] * alpha + rsum;
            mrow[ti] = mnew;
            #pragma unroll
            for (int dt = 0; dt < 4; ++dt) accO[ti][dt] *= alpha;
            #pragma unroll
            for (int tj = 0; tj < 8; ++tj)
                pb[ti][tj] = (bf16x4){(bf16_t)s[tj][0], (bf16_t)s[tj][1],
                                      (bf16_t)s[tj][2], (bf16_t)s[tj][3]};
        }

        // PV: O^T += V^T(A) x P^T(B), 16x16x16; V^T frag shared across ti
        #pragma unroll
        for (int ks = 0; ks < 8; ++ks)
            #pragma unroll
            for (int dt = 0; dt < 4; ++dt) {
                const bf16x4 va = *(const bf16x4*)&VT[(dt * 16 + l16) * VT_STRIDE + ks * 16 + g4 * 4];
                accO[0][dt] = mfma16(va, pb[0][ks], accO[0][dt]);
                accO[1][dt] = mfma16(va, pb[1][ks], accO[1][dt]);
            }
    }

    // epilogue: transpose O^T -> attn[q][d] via LDS (2 passes of 64 rows)
    for (int pass = 0; pass < 2; ++pass) {
        __syncthreads();
        if ((wave >> 1) == pass) {
            for (int ti = 0; ti < 2; ++ti) {
                const float rl = 1.0f / lrow[ti];
                const int rowrel = (wave & 1) * 32 + ti * 16 + l16;
                #pragma unroll
                for (int dt = 0; dt < 4; ++dt)
                    #pragma unroll
                    for (int r = 0; r < 4; ++r)
                        Os[rowrel * OS_STRIDE + dt * 16 + g4 * 4 + r] = accO[ti][dt][r] * rl;
            }
        }
        __syncthreads();
        const int c4 = (t & 15) * 4;
        for (int it = 0; it < 4; ++it) {
            const int rr = (t >> 4) + it * 16;
            const float4 vv = *(const float4*)&Os[rr * OS_STRIDE + c4];
            *(float4*)&attn[(size_t)(b * L_ + q0 + pass * 64 + rr) * D_ + h * DH_ + c4] = vv;
        }
    }
}

extern "C" void kernel_launch(void* const* d_in, const int* in_sizes, int n_in,
                              void* d_out, int out_size, void* d_ws, size_t ws_size,
                              hipStream_t stream) {
    const float* x    = (const float*)d_in[0];
    const int*   mask = (const int*)d_in[1];
    const float* Wq   = (const float*)d_in[2];
    const float* bq   = (const float*)d_in[3];
    const float* Wk   = (const float*)d_in[4];
    const float* bk   = (const float*)d_in[5];
    const float* Wv   = (const float*)d_in[6];
    const float* bv   = (const float*)d_in[7];
    const float* g1   = (const float*)d_in[8];
    const float* b1   = (const float*)d_in[9];
    const float* g2   = (const float*)d_in[10];
    const float* b2   = (const float*)d_in[11];
    const float* Wo1  = (const float*)d_in[12];
    const float* bo1  = (const float*)d_in[13];
    const float* Wo2  = (const float*)d_in[14];
    const float* bo2  = (const float*)d_in[15];

    char* ws = (char*)d_ws;
    const size_t MBs = 1ull << 20;
    bf16_t* WqkvT = (bf16_t*)(ws + 0 * MBs);          // [3072][1024] bf16, 6 MB
    bf16_t* Wo1T  = (bf16_t*)(ws + 6 * MBs);
    bf16_t* Wo2T  = (bf16_t*)(ws + 8 * MBs);
    bf16_t* h1    = (bf16_t*)(ws + 10 * MBs);
    bf16_t* qb    = (bf16_t*)(ws + 26 * MBs);
    bf16_t* kb    = (bf16_t*)(ws + 42 * MBs);
    bf16_t* vb    = (bf16_t*)(ws + 58 * MBs);
    float*  attn  = (float*)(ws + 74 * MBs);
    float*  resid = (float*)(ws + 106 * MBs);
    bf16_t* h2    = qb;   // reuse
    bf16_t* gact  = kb;   // reuse

    const dim3 tb(32, 8), tg(32, 32);
    transpose_bf16<<<tg, tb, 0, stream>>>(Wq, WqkvT);
    transpose_bf16<<<tg, tb, 0, stream>>>(Wk, WqkvT + (size_t)D_ * D_);
    transpose_bf16<<<tg, tb, 0, stream>>>(Wv, WqkvT + (size_t)2 * D_ * D_);
    transpose_bf16<<<tg, tb, 0, stream>>>(Wo1, Wo1T);
    transpose_bf16<<<tg, tb, 0, stream>>>(Wo2, Wo2T);

    ln1_kernel<<<M_, 256, 0, stream>>>(x, g1, b1, h1);

    gemm_qkv<<<dim3(M_ / 128, 3 * D_ / 128), 256, 0, stream>>>(h1, WqkvT, bq, bk, bv, qb, kb, vb);

    attn_kernel<<<dim3(L_ / 128, B_ * H_), 256, 0, stream>>>(qb, kb, vb, mask, attn);

    add_ln2_kernel<<<M_, 256, 0, stream>>>(x, attn, g2, b2, resid, h2);

    const dim3 gg(M_ / 128, D_ / 128);
    gemm_bt<1><<<gg, 256, 0, stream>>>(h2, Wo1T, bo1, nullptr, gact, nullptr);
    gemm_bt<2><<<gg, 256, 0, stream>>>(gact, Wo2T, bo2, resid, nullptr, (float*)d_out);
}

// Round 3
// 381.304 us; speedup vs baseline: 1.5197x; 1.2829x over previous
//
#include <hip/hip_runtime.h>
#include <stdint.h>
#include <math.h>

typedef __bf16 bf16_t;
typedef __bf16 bf16x8 __attribute__((ext_vector_type(8)));
typedef __bf16 bf16x4 __attribute__((ext_vector_type(4)));
typedef short short4v __attribute__((ext_vector_type(4)));
typedef float f32x4 __attribute__((ext_vector_type(4)));

#define B_ 4
#define L_ 2048
#define D_ 1024
#define H_ 16
#define DH_ 64
#define M_ (B_ * L_)   // 8192
#define LOG2E 1.4426950408889634f
#define QSCALE 0.18033688011112042f   // 0.125 * log2(e): softmax done in exp2 domain

__device__ __forceinline__ void gload16(const bf16_t* gsrc, bf16_t* ldst) {
    __builtin_amdgcn_global_load_lds(
        (__attribute__((address_space(1))) void*)(void*)(gsrc),
        (__attribute__((address_space(3))) void*)(ldst), 16, 0, 0);
}

__device__ __forceinline__ float gelu_exact(float v) {
    return 0.5f * v * (1.0f + erff(v * 0.70710678118654752f));
}

__device__ __forceinline__ float fast_exp2(float x) {
#if __has_builtin(__builtin_amdgcn_exp2f)
    return __builtin_amdgcn_exp2f(x);
#else
    return exp2f(x);
#endif
}

__device__ __forceinline__ f32x4 mfma16(bf16x4 a, bf16x4 b, f32x4 c) {
#if __has_builtin(__builtin_amdgcn_mfma_f32_16x16x16_bf16)
    return __builtin_amdgcn_mfma_f32_16x16x16_bf16(a, b, c, 0, 0, 0);
#else
    union U { bf16x4 h; short4v s; };
    U ua, ub; ua.h = a; ub.h = b;
    return __builtin_amdgcn_mfma_f32_16x16x16bf16_1k(ua.s, ub.s, c, 0, 0, 0);
#endif
}

// ---------------- 5 weight transposes fused: WT[n][k] = W[k][n], fp32 -> bf16 ----------------
__global__ __launch_bounds__(256) void transpose5(const float* __restrict__ W0, const float* __restrict__ W1,
                                                  const float* __restrict__ W2, const float* __restrict__ W3,
                                                  const float* __restrict__ W4,
                                                  bf16_t* __restrict__ T0, bf16_t* __restrict__ T1,
                                                  bf16_t* __restrict__ T2, bf16_t* __restrict__ T3,
                                                  bf16_t* __restrict__ T4) {
    const float* W; bf16_t* T;
    switch (blockIdx.z) {
        case 0: W = W0; T = T0; break;
        case 1: W = W1; T = T1; break;
        case 2: W = W2; T = T2; break;
        case 3: W = W3; T = T3; break;
        default: W = W4; T = T4; break;
    }
    __shared__ float tile[32][33];
    const int x = threadIdx.x, y0 = threadIdx.y;
    const int bx = blockIdx.x * 32, by = blockIdx.y * 32;
    for (int kk = 0; kk < 4; ++kk)
        tile[y0 + kk * 8][x] = W[(size_t)(by + y0 + kk * 8) * D_ + bx + x];
    __syncthreads();
    for (int kk = 0; kk < 4; ++kk)
        T[(size_t)(bx + y0 + kk * 8) * D_ + by + x] = (bf16_t)tile[x][y0 + kk * 8];
}

// ---------------- mask -> additive bias (0 or -1e30) ----------------
__global__ __launch_bounds__(256) void maskbias_kernel(const int* __restrict__ mask,
                                                       float* __restrict__ mb) {
    const int i = blockIdx.x * 256 + threadIdx.x;
    mb[i] = mask[i] ? 0.f : -1.0e30f;
}

// ---------------- LayerNorm 1: x -> h (bf16) ----------------
__global__ __launch_bounds__(256) void ln1_kernel(const float* __restrict__ x,
                                                  const float* __restrict__ g,
                                                  const float* __restrict__ b,
                                                  bf16_t* __restrict__ h) {
    const int row = blockIdx.x, t = threadIdx.x;
    const float4 v = *(const float4*)(x + (size_t)row * D_ + t * 4);
    float s = v.x + v.y + v.z + v.w;
    float s2 = v.x * v.x + v.y * v.y + v.z * v.z + v.w * v.w;
    for (int m = 1; m < 64; m <<= 1) { s += __shfl_xor(s, m, 64); s2 += __shfl_xor(s2, m, 64); }
    __shared__ float red[2][4];
    if ((t & 63) == 0) { red[0][t >> 6] = s; red[1][t >> 6] = s2; }
    __syncthreads();
    s = red[0][0] + red[0][1] + red[0][2] + red[0][3];
    s2 = red[1][0] + red[1][1] + red[1][2] + red[1][3];
    const float mean = s * (1.f / 1024.f);
    const float var = s2 * (1.f / 1024.f) - mean * mean;
    const float rstd = rsqrtf(var + 1e-6f);
    const float4 gv = *(const float4*)(g + t * 4);
    const float4 bv = *(const float4*)(b + t * 4);
    union { bf16_t h4[4]; uint2 u; } o;
    o.h4[0] = (bf16_t)((v.x - mean) * rstd * gv.x + bv.x);
    o.h4[1] = (bf16_t)((v.y - mean) * rstd * gv.y + bv.y);
    o.h4[2] = (bf16_t)((v.z - mean) * rstd * gv.z + bv.z);
    o.h4[3] = (bf16_t)((v.w - mean) * rstd * gv.w + bv.w);
    *(uint2*)(h + (size_t)row * D_ + t * 4) = o.u;
}

// ---------------- residual add (bf16 attn) + LayerNorm 2 -> resid bf16, h bf16 ----------------
__global__ __launch_bounds__(256) void add_ln2_kernel(const float* __restrict__ x,
                                                      const bf16_t* __restrict__ attnb,
                                                      const float* __restrict__ g,
                                                      const float* __restrict__ b,
                                                      bf16_t* __restrict__ residb,
                                                      bf16_t* __restrict__ h) {
    const int row = blockIdx.x, t = threadIdx.x;
    const float4 xv = *(const float4*)(x + (size_t)row * D_ + t * 4);
    union { uint2 u; bf16_t h4[4]; } ai;
    ai.u = *(const uint2*)(attnb + (size_t)row * D_ + t * 4);
    float4 v;
    v.x = xv.x + (float)ai.h4[0]; v.y = xv.y + (float)ai.h4[1];
    v.z = xv.z + (float)ai.h4[2]; v.w = xv.w + (float)ai.h4[3];
    union { bf16_t h4[4]; uint2 u; } rs;
    rs.h4[0] = (bf16_t)v.x; rs.h4[1] = (bf16_t)v.y; rs.h4[2] = (bf16_t)v.z; rs.h4[3] = (bf16_t)v.w;
    *(uint2*)(residb + (size_t)row * D_ + t * 4) = rs.u;
    float s = v.x + v.y + v.z + v.w;
    float s2 = v.x * v.x + v.y * v.y + v.z * v.z + v.w * v.w;
    for (int m = 1; m < 64; m <<= 1) { s += __shfl_xor(s, m, 64); s2 += __shfl_xor(s2, m, 64); }
    __shared__ float red[2][4];
    if ((t & 63) == 0) { red[0][t >> 6] = s; red[1][t >> 6] = s2; }
    __syncthreads();
    s = red[0][0] + red[0][1] + red[0][2] + red[0][3];
    s2 = red[1][0] + red[1][1] + red[1][2] + red[1][3];
    const float mean = s * (1.f / 1024.f);
    const float var = s2 * (1.f / 1024.f) - mean * mean;
    const float rstd = rsqrtf(var + 1e-6f);
    const float4 gv = *(const float4*)(g + t * 4);
    const float4 bv = *(const float4*)(b + t * 4);
    union { bf16_t h4[4]; uint2 u; } o;
    o.h4[0] = (bf16_t)((v.x - mean) * rstd * gv.x + bv.x);
    o.h4[1] = (bf16_t)((v.y - mean) * rstd * gv.y + bv.y);
    o.h4[2] = (bf16_t)((v.z - mean) * rstd * gv.z + bv.z);
    o.h4[3] = (bf16_t)((v.w - mean) * rstd * gv.w + bv.w);
    *(uint2*)(h + (size_t)row * D_ + t * 4) = o.u;
}

// ---------------- fused QKV GEMM; q scaled by 0.125*log2e ----------------
__global__ __launch_bounds__(256) void gemm_qkv(const bf16_t* __restrict__ A,
                                                const bf16_t* __restrict__ BT,
                                                const float* __restrict__ bq,
                                                const float* __restrict__ bk,
                                                const float* __restrict__ bv,
                                                bf16_t* __restrict__ qb,
                                                bf16_t* __restrict__ kb,
                                                bf16_t* __restrict__ vb) {
    constexpr int K = 1024;
    __shared__ bf16_t As[128 * 32];
    __shared__ bf16_t Bs[128 * 32];
    const int t = threadIdx.x;
    const int wave = t >> 6, lane = t & 63;
    const int l16 = lane & 15, g4 = lane >> 4;
    const int bm = blockIdx.x * 128, bn = blockIdx.y * 128;
    const int wm = (wave >> 1) * 64, wn = (wave & 1) * 64;

    f32x4 acc[4][4];
    for (int i = 0; i < 4; ++i)
        for (int j = 0; j < 4; ++j) acc[i][j] = (f32x4){0.f, 0.f, 0.f, 0.f};

    const int ar = t >> 2, ak = (t & 3) * 8;
    const bf16_t* Ag = A + (size_t)(bm + ar) * K + ak;
    const bf16_t* Bg = BT + (size_t)(bn + ar) * K + ak;
    bf16_t* Al = As + t * 8;
    bf16_t* Bl = Bs + t * 8;

    for (int kk = 0; kk < K; kk += 32) {
        __syncthreads();
        gload16(Ag + kk, Al);
        gload16(Ag + (size_t)64 * K + kk, Al + 2048);
        gload16(Bg + kk, Bl);
        gload16(Bg + (size_t)64 * K + kk, Bl + 2048);
        __syncthreads();
        bf16x8 af[4], bfr[4];
        for (int i = 0; i < 4; ++i)
            af[i] = *(const bf16x8*)&As[(wm + i * 16 + l16) * 32 + g4 * 8];
        for (int j = 0; j < 4; ++j)
            bfr[j] = *(const bf16x8*)&Bs[(wn + j * 16 + l16) * 32 + g4 * 8];
        for (int i = 0; i < 4; ++i)
            for (int j = 0; j < 4; ++j)
                acc[i][j] = __builtin_amdgcn_mfma_f32_16x16x32_bf16(af[i], bfr[j], acc[i][j], 0, 0, 0);
    }

    const int which = bn >> 10;             // 0=q, 1=k, 2=v
    const int c0 = bn & 1023;
    const float* bias = (which == 0) ? bq : (which == 1) ? bk : bv;
    bf16_t* ob = (which == 0) ? qb : (which == 1) ? kb : vb;
    const float scale = (which == 0) ? QSCALE : 1.0f;

    for (int i = 0; i < 4; ++i)
        for (int j = 0; j < 4; ++j) {
            const int col = c0 + wn + j * 16 + l16;
            const float bvv = bias[col];
            const int row0 = bm + wm + i * 16 + g4 * 4;
            for (int r = 0; r < 4; ++r) {
                const float vv = (acc[i][j][r] + bvv) * scale;
                ob[(size_t)(row0 + r) * D_ + col] = (bf16_t)vv;
            }
        }
}

// ---------------- GEMM: MODE 1 gelu->bf16, MODE 2 +resid(bf16)->f32 ----------------
template <int MODE>
__global__ __launch_bounds__(256) void gemm_bt(const bf16_t* __restrict__ A,
                                               const bf16_t* __restrict__ BT,
                                               const float* __restrict__ bias,
                                               const bf16_t* __restrict__ residb,
                                               bf16_t* __restrict__ outb,
                                               float* __restrict__ outf) {
    constexpr int K = 1024, N = 1024;
    __shared__ bf16_t As[128 * 32];
    __shared__ bf16_t Bs[128 * 32];
    const int t = threadIdx.x;
    const int wave = t >> 6, lane = t & 63;
    const int l16 = lane & 15, g4 = lane >> 4;
    const int bm = blockIdx.x * 128, bn = blockIdx.y * 128;
    const int wm = (wave >> 1) * 64, wn = (wave & 1) * 64;

    f32x4 acc[4][4];
    for (int i = 0; i < 4; ++i)
        for (int j = 0; j < 4; ++j) acc[i][j] = (f32x4){0.f, 0.f, 0.f, 0.f};

    const int ar = t >> 2, ak = (t & 3) * 8;
    const bf16_t* Ag = A + (size_t)(bm + ar) * K + ak;
    const bf16_t* Bg = BT + (size_t)(bn + ar) * K + ak;
    bf16_t* Al = As + t * 8;
    bf16_t* Bl = Bs + t * 8;

    for (int kk = 0; kk < K; kk += 32) {
        __syncthreads();
        gload16(Ag + kk, Al);
        gload16(Ag + (size_t)64 * K + kk, Al + 2048);
        gload16(Bg + kk, Bl);
        gload16(Bg + (size_t)64 * K + kk, Bl + 2048);
        __syncthreads();
        bf16x8 af[4], bfr[4];
        for (int i = 0; i < 4; ++i)
            af[i] = *(const bf16x8*)&As[(wm + i * 16 + l16) * 32 + g4 * 8];
        for (int j = 0; j < 4; ++j)
            bfr[j] = *(const bf16x8*)&Bs[(wn + j * 16 + l16) * 32 + g4 * 8];
        for (int i = 0; i < 4; ++i)
            for (int j = 0; j < 4; ++j)
                acc[i][j] = __builtin_amdgcn_mfma_f32_16x16x32_bf16(af[i], bfr[j], acc[i][j], 0, 0, 0);
    }

    for (int i = 0; i < 4; ++i)
        for (int j = 0; j < 4; ++j) {
            const int col = bn + wn + j * 16 + l16;
            const float bv = bias[col];
            const int row0 = bm + wm + i * 16 + g4 * 4;
            for (int r = 0; r < 4; ++r) {
                float vv = acc[i][j][r] + bv;
                const size_t idx = (size_t)(row0 + r) * N + col;
                if (MODE == 1) {
                    outb[idx] = (bf16_t)gelu_exact(vv);
                } else {
                    outf[idx] = vv + (float)residb[idx];
                }
            }
        }
}

// ---------------- flash attention v3: no-max exp2 softmax, l via MFMA ones-row ----------------
// 1-D grid of 1024, XCD-swizzled so each XCD owns 8 complete (b,h) heads.
// q pre-scaled by 0.125*log2e; maskbias additive (0 / -1e30).
#define KS_STRIDE 72
#define VT_STRIDE 152
__global__ __launch_bounds__(256, 3) void attn_kernel(const bf16_t* __restrict__ q,
                                                      const bf16_t* __restrict__ k,
                                                      const bf16_t* __restrict__ v,
                                                      const float* __restrict__ maskbias,
                                                      bf16_t* __restrict__ attnb) {
    __shared__ char smem[18432 + 19456];
    bf16_t* Ks = (bf16_t*)smem;                  // [128][72]
    bf16_t* VT = (bf16_t*)(smem + 18432);        // [64][152]  (V^T: d x key)
    bf16_t* Os = (bf16_t*)smem;                  // epilogue overlay [128][72] bf16

    const int t = threadIdx.x;
    const int wave = t >> 6, lane = t & 63;
    const int l16 = lane & 15, g4 = lane >> 4;
    // XCD swizzle: id%8 = XCD (round-robin dispatch); each XCD gets bh = xcd*8 .. xcd*8+7
    const int id = blockIdx.x;
    const int xcd = id & 7, seq = id >> 3;
    const int bh = xcd * 8 + (seq >> 4);
    const int b = bh >> 4, h = bh & 15;
    const int q0 = (seq & 15) * 128;

    // Q fragments (B-operand of QK^T): lane n=q(l16), holds d = c*32 + g4*8 + j
    bf16x8 qf[2][2];
    for (int ti = 0; ti < 2; ++ti)
        for (int c = 0; c < 2; ++c)
            qf[ti][c] = *(const bf16x8*)(q + (size_t)(b * L_ + q0 + wave * 32 + ti * 16 + l16) * D_ +
                                         h * DH_ + c * 32 + g4 * 8);

    f32x4 accO[2][5];   // [ti][dt]; dt=4 is the ones-row = running row-sum l
    for (int ti = 0; ti < 2; ++ti)
        for (int dt = 0; dt < 5; ++dt) accO[ti][dt] = (f32x4){0.f, 0.f, 0.f, 0.f};

    const bf16_t one_or_zero = (l16 == 0) ? (bf16_t)1.0f : (bf16_t)0.0f;
    const bf16x4 ones4 = (bf16x4){one_or_zero, one_or_zero, one_or_zero, one_or_zero};

    for (int k0 = 0; k0 < L_; k0 += 128) {
        __syncthreads();
        // stage K [128][64] row-major pad 72, vector 16B writes
        for (int cc = 0; cc < 4; ++cc) {
            const int c = t + cc * 256;
            const int row = c >> 3, off = (c & 7) * 8;
            *(uint4*)&Ks[row * KS_STRIDE + off] =
                *(const uint4*)(k + (size_t)(b * L_ + k0 + row) * D_ + h * DH_ + off);
        }
        // stage V^T [64][128]: scalar global reads (lane=d -> coalesced 128B), 16B LDS writes
        {
            const int d = t & 63, kg = t >> 6;
            for (int k8 = 0; k8 < 4; ++k8) {
                union { uint4 u; bf16_t e[8]; } tv;
                #pragma unroll
                for (int i = 0; i < 8; ++i)
                    tv.e[i] = v[(size_t)(b * L_ + k0 + kg * 32 + k8 * 8 + i) * D_ + h * DH_ + d];
                *(uint4*)&VT[d * VT_STRIDE + kg * 32 + k8 * 8] = tv.u;
            }
        }
        __syncthreads();

        // S^T = K Q^T (both ti), C-layout: col=l16=q, row=g4*4+r=key
        f32x4 s0[8], s1[8];
        #pragma unroll
        for (int tj = 0; tj < 8; ++tj) {
            const bf16x8 kf0 = *(const bf16x8*)&Ks[(tj * 16 + l16) * KS_STRIDE + g4 * 8];
            const bf16x8 kf1 = *(const bf16x8*)&Ks[(tj * 16 + l16) * KS_STRIDE + 32 + g4 * 8];
            f32x4 a = (f32x4){0.f, 0.f, 0.f, 0.f};
            a = __builtin_amdgcn_mfma_f32_16x16x32_bf16(kf0, qf[0][0], a, 0, 0, 0);
            a = __builtin_amdgcn_mfma_f32_16x16x32_bf16(kf1, qf[0][1], a, 0, 0, 0);
            s0[tj] = a;
            f32x4 a2 = (f32x4){0.f, 0.f, 0.f, 0.f};
            a2 = __builtin_amdgcn_mfma_f32_16x16x32_bf16(kf0, qf[1][0], a2, 0, 0, 0);
            a2 = __builtin_amdgcn_mfma_f32_16x16x32_bf16(kf1, qf[1][1], a2, 0, 0, 0);
            s1[tj] = a2;
        }

        // softmax numerators: p = exp2(s + maskbias); no max-tracking (|s| << 80)
        bf16x4 pb0[8], pb1[8];
        #pragma unroll
        for (int tj = 0; tj < 8; ++tj) {
            const float4 mb = *(const float4*)&maskbias[b * L_ + k0 + tj * 16 + g4 * 4];
            float p00 = fast_exp2(s0[tj][0] + mb.x), p01 = fast_exp2(s0[tj][1] + mb.y);
            float p02 = fast_exp2(s0[tj][2] + mb.z), p03 = fast_exp2(s0[tj][3] + mb.w);
            float p10 = fast_exp2(s1[tj][0] + mb.x), p11 = fast_exp2(s1[tj][1] + mb.y);
            float p12 = fast_exp2(s1[tj][2] + mb.z), p13 = fast_exp2(s1[tj][3] + mb.w);
            pb0[tj] = (bf16x4){(bf16_t)p00, (bf16_t)p01, (bf16_t)p02, (bf16_t)p03};
            pb1[tj] = (bf16x4){(bf16_t)p10, (bf16_t)p11, (bf16_t)p12, (bf16_t)p13};
        }

        // PV: O^T += V^T(A) x P^T(B); dt=4 uses constant ones-row -> accumulates l
        #pragma unroll
        for (int ks = 0; ks < 8; ++ks) {
            #pragma unroll
            for (int dt = 0; dt < 4; ++dt) {
                const bf16x4 va = *(const bf16x4*)&VT[(dt * 16 + l16) * VT_STRIDE + ks * 16 + g4 * 4];
                accO[0][dt] = mfma16(va, pb0[ks], accO[0][dt]);
                accO[1][dt] = mfma16(va, pb1[ks], accO[1][dt]);
            }
            accO[0][4] = mfma16(ones4, pb0[ks], accO[0][4]);
            accO[1][4] = mfma16(ones4, pb1[ks], accO[1][4]);
        }
    }

    // epilogue: normalize by l (broadcast from g4==0,r==0 lane), transpose via LDS, bf16 out
    __syncthreads();
    for (int ti = 0; ti < 2; ++ti) {
        const float lv = __shfl(accO[ti][4][0], l16, 64);
        const float rl = 1.0f / lv;
        #pragma unroll
        for (int dt = 0; dt < 4; ++dt) {
            bf16x4 o4 = (bf16x4){(bf16_t)(accO[ti][dt][0] * rl), (bf16_t)(accO[ti][dt][1] * rl),
                                 (bf16_t)(accO[ti][dt][2] * rl), (bf16_t)(accO[ti][dt][3] * rl)};
            *(bf16x4*)&Os[(wave * 32 + ti * 16 + l16) * KS_STRIDE + dt * 16 + g4 * 4] = o4;
        }
    }
    __syncthreads();
    for (int cc = 0; cc < 4; ++cc) {
        const int c2 = t + cc * 256;
        const int row = c2 >> 3, k8 = c2 & 7;
        const uint4 vv = *(const uint4*)&Os[row * KS_STRIDE + k8 * 8];
        *(uint4*)&attnb[(size_t)(b * L_ + q0 + row) * D_ + h * DH_ + k8 * 8] = vv;
    }
}

extern "C" void kernel_launch(void* const* d_in, const int* in_sizes, int n_in,
                              void* d_out, int out_size, void* d_ws, size_t ws_size,
                              hipStream_t stream) {
    const float* x    = (const float*)d_in[0];
    const int*   mask = (const int*)d_in[1];
    const float* Wq   = (const float*)d_in[2];
    const float* bq   = (const float*)d_in[3];
    const float* Wk   = (const float*)d_in[4];
    const float* bk   = (const float*)d_in[5];
    const float* Wv   = (const float*)d_in[6];
    const float* bv   = (const float*)d_in[7];
    const float* g1   = (const float*)d_in[8];
    const float* b1   = (const float*)d_in[9];
    const float* g2   = (const float*)d_in[10];
    const float* b2   = (const float*)d_in[11];
    const float* Wo1  = (const float*)d_in[12];
    const float* bo1  = (const float*)d_in[13];
    const float* Wo2  = (const float*)d_in[14];
    const float* bo2  = (const float*)d_in[15];

    char* ws = (char*)d_ws;
    const size_t MBs = 1ull << 20;
    bf16_t* WqkvT = (bf16_t*)(ws + 0 * MBs);          // [3072][1024] bf16
    bf16_t* Wo1T  = (bf16_t*)(ws + 6 * MBs);
    bf16_t* Wo2T  = (bf16_t*)(ws + 8 * MBs);
    bf16_t* h1    = (bf16_t*)(ws + 10 * MBs);
    bf16_t* qb    = (bf16_t*)(ws + 26 * MBs);
    bf16_t* kb    = (bf16_t*)(ws + 42 * MBs);
    bf16_t* vb    = (bf16_t*)(ws + 58 * MBs);
    bf16_t* attnb = (bf16_t*)(ws + 74 * MBs);
    bf16_t* residb= (bf16_t*)(ws + 90 * MBs);
    float*  mbias = (float*)(ws + 106 * MBs);
    bf16_t* h2    = qb;   // reuse
    bf16_t* gact  = kb;   // reuse

    transpose5<<<dim3(32, 32, 5), dim3(32, 8), 0, stream>>>(
        Wq, Wk, Wv, Wo1, Wo2,
        WqkvT, WqkvT + (size_t)D_ * D_, WqkvT + (size_t)2 * D_ * D_, Wo1T, Wo2T);

    maskbias_kernel<<<M_ / 256, 256, 0, stream>>>(mask, mbias);

    ln1_kernel<<<M_, 256, 0, stream>>>(x, g1, b1, h1);

    gemm_qkv<<<dim3(M_ / 128, 3 * D_ / 128), 256, 0, stream>>>(h1, WqkvT, bq, bk, bv, qb, kb, vb);

    attn_kernel<<<dim3(1024), 256, 0, stream>>>(qb, kb, vb, mbias, attnb);

    add_ln2_kernel<<<M_, 256, 0, stream>>>(x, attnb, g2, b2, residb, h2);

    const dim3 gg(M_ / 128, D_ / 128);
    gemm_bt<1><<<gg, 256, 0, stream>>>(h2, Wo1T, bo1, nullptr, gact, nullptr);
    gemm_bt<2><<<gg, 256, 0, stream>>>(gact, Wo2T, bo2, residb, nullptr, (float*)d_out);
}

// Round 4
// 374.943 us; speedup vs baseline: 1.5454x; 1.0170x over previous
//
#include <hip/hip_runtime.h>
#include <stdint.h>
#include <math.h>

typedef __bf16 bf16_t;
typedef __bf16 bf16x8 __attribute__((ext_vector_type(8)));
typedef __bf16 bf16x4 __attribute__((ext_vector_type(4)));
typedef short short4v __attribute__((ext_vector_type(4)));
typedef float f32x4 __attribute__((ext_vector_type(4)));

#define B_ 4
#define L_ 2048
#define D_ 1024
#define H_ 16
#define DH_ 64
#define M_ (B_ * L_)   // 8192
#define LOG2E 1.4426950408889634f
#define QSCALE 0.18033688011112042f   // 0.125 * log2(e): softmax done in exp2 domain

__device__ __forceinline__ void gload16(const bf16_t* gsrc, bf16_t* ldst) {
    __builtin_amdgcn_global_load_lds(
        (__attribute__((address_space(1))) void*)(void*)(gsrc),
        (__attribute__((address_space(3))) void*)(ldst), 16, 0, 0);
}

__device__ __forceinline__ float gelu_exact(float v) {
    return 0.5f * v * (1.0f + erff(v * 0.70710678118654752f));
}

__device__ __forceinline__ float fast_exp2(float x) {
#if __has_builtin(__builtin_amdgcn_exp2f)
    return __builtin_amdgcn_exp2f(x);
#else
    return exp2f(x);
#endif
}

__device__ __forceinline__ f32x4 mfma16(bf16x4 a, bf16x4 b, f32x4 c) {
#if __has_builtin(__builtin_amdgcn_mfma_f32_16x16x16_bf16)
    return __builtin_amdgcn_mfma_f32_16x16x16_bf16(a, b, c, 0, 0, 0);
#else
    union U { bf16x4 h; short4v s; };
    U ua, ub; ua.h = a; ub.h = b;
    return __builtin_amdgcn_mfma_f32_16x16x16bf16_1k(ua.s, ub.s, c, 0, 0, 0);
#endif
}

// ---------------- 5 weight transposes fused: WT[n][k] = W[k][n], fp32 -> bf16 ----------------
__global__ __launch_bounds__(256) void transpose5(const float* __restrict__ W0, const float* __restrict__ W1,
                                                  const float* __restrict__ W2, const float* __restrict__ W3,
                                                  const float* __restrict__ W4,
                                                  bf16_t* __restrict__ T0, bf16_t* __restrict__ T1,
                                                  bf16_t* __restrict__ T2, bf16_t* __restrict__ T3,
                                                  bf16_t* __restrict__ T4) {
    const float* W; bf16_t* T;
    switch (blockIdx.z) {
        case 0: W = W0; T = T0; break;
        case 1: W = W1; T = T1; break;
        case 2: W = W2; T = T2; break;
        case 3: W = W3; T = T3; break;
        default: W = W4; T = T4; break;
    }
    __shared__ float tile[32][33];
    const int x = threadIdx.x, y0 = threadIdx.y;
    const int bx = blockIdx.x * 32, by = blockIdx.y * 32;
    for (int kk = 0; kk < 4; ++kk)
        tile[y0 + kk * 8][x] = W[(size_t)(by + y0 + kk * 8) * D_ + bx + x];
    __syncthreads();
    for (int kk = 0; kk < 4; ++kk)
        T[(size_t)(bx + y0 + kk * 8) * D_ + by + x] = (bf16_t)tile[x][y0 + kk * 8];
}

// ---------------- mask -> additive bias (0 or -1e30) ----------------
__global__ __launch_bounds__(256) void maskbias_kernel(const int* __restrict__ mask,
                                                       float* __restrict__ mb) {
    const int i = blockIdx.x * 256 + threadIdx.x;
    mb[i] = mask[i] ? 0.f : -1.0e30f;
}

// ---------------- per-head V transpose: vb[b,key,h,d] -> vt[b,h,d,key] ----------------
#define VTR_STRIDE 76
__global__ __launch_bounds__(256) void vtrans_kernel(const bf16_t* __restrict__ vb,
                                                     bf16_t* __restrict__ vt) {
    __shared__ bf16_t tile[128 * VTR_STRIDE];
    const int t = threadIdx.x;
    const int bh = blockIdx.y, b = bh >> 4, h = bh & 15;
    const int k0 = blockIdx.x * 128;
    // load coalesced: [key][d]
    #pragma unroll
    for (int it = 0; it < 4; ++it) {
        const int row = it * 32 + (t >> 3), c8 = (t & 7) * 8;
        *(uint4*)&tile[row * VTR_STRIDE + c8] =
            *(const uint4*)(vb + (size_t)(b * L_ + k0 + row) * D_ + h * DH_ + c8);
    }
    __syncthreads();
    // store coalesced: [d][key]
    #pragma unroll
    for (int it = 0; it < 4; ++it) {
        const int d = it * 16 + (t >> 4), kg = (t & 15) * 8;
        union { uint4 u; bf16_t e[8]; } tv;
        #pragma unroll
        for (int j = 0; j < 8; ++j) tv.e[j] = tile[(kg + j) * VTR_STRIDE + d];
        *(uint4*)&vt[((size_t)bh * DH_ + d) * L_ + k0 + kg] = tv.u;
    }
}

// ---------------- LayerNorm 1: x -> h (bf16) ----------------
__global__ __launch_bounds__(256) void ln1_kernel(const float* __restrict__ x,
                                                  const float* __restrict__ g,
                                                  const float* __restrict__ b,
                                                  bf16_t* __restrict__ h) {
    const int row = blockIdx.x, t = threadIdx.x;
    const float4 v = *(const float4*)(x + (size_t)row * D_ + t * 4);
    float s = v.x + v.y + v.z + v.w;
    float s2 = v.x * v.x + v.y * v.y + v.z * v.z + v.w * v.w;
    for (int m = 1; m < 64; m <<= 1) { s += __shfl_xor(s, m, 64); s2 += __shfl_xor(s2, m, 64); }
    __shared__ float red[2][4];
    if ((t & 63) == 0) { red[0][t >> 6] = s; red[1][t >> 6] = s2; }
    __syncthreads();
    s = red[0][0] + red[0][1] + red[0][2] + red[0][3];
    s2 = red[1][0] + red[1][1] + red[1][2] + red[1][3];
    const float mean = s * (1.f / 1024.f);
    const float var = s2 * (1.f / 1024.f) - mean * mean;
    const float rstd = rsqrtf(var + 1e-6f);
    const float4 gv = *(const float4*)(g + t * 4);
    const float4 bv = *(const float4*)(b + t * 4);
    union { bf16_t h4[4]; uint2 u; } o;
    o.h4[0] = (bf16_t)((v.x - mean) * rstd * gv.x + bv.x);
    o.h4[1] = (bf16_t)((v.y - mean) * rstd * gv.y + bv.y);
    o.h4[2] = (bf16_t)((v.z - mean) * rstd * gv.z + bv.z);
    o.h4[3] = (bf16_t)((v.w - mean) * rstd * gv.w + bv.w);
    *(uint2*)(h + (size_t)row * D_ + t * 4) = o.u;
}

// ---------------- residual add (bf16 attn) + LayerNorm 2 -> resid bf16, h bf16 ----------------
__global__ __launch_bounds__(256) void add_ln2_kernel(const float* __restrict__ x,
                                                      const bf16_t* __restrict__ attnb,
                                                      const float* __restrict__ g,
                                                      const float* __restrict__ b,
                                                      bf16_t* __restrict__ residb,
                                                      bf16_t* __restrict__ h) {
    const int row = blockIdx.x, t = threadIdx.x;
    const float4 xv = *(const float4*)(x + (size_t)row * D_ + t * 4);
    union { uint2 u; bf16_t h4[4]; } ai;
    ai.u = *(const uint2*)(attnb + (size_t)row * D_ + t * 4);
    float4 v;
    v.x = xv.x + (float)ai.h4[0]; v.y = xv.y + (float)ai.h4[1];
    v.z = xv.z + (float)ai.h4[2]; v.w = xv.w + (float)ai.h4[3];
    union { bf16_t h4[4]; uint2 u; } rs;
    rs.h4[0] = (bf16_t)v.x; rs.h4[1] = (bf16_t)v.y; rs.h4[2] = (bf16_t)v.z; rs.h4[3] = (bf16_t)v.w;
    *(uint2*)(residb + (size_t)row * D_ + t * 4) = rs.u;
    float s = v.x + v.y + v.z + v.w;
    float s2 = v.x * v.x + v.y * v.y + v.z * v.z + v.w * v.w;
    for (int m = 1; m < 64; m <<= 1) { s += __shfl_xor(s, m, 64); s2 += __shfl_xor(s2, m, 64); }
    __shared__ float red[2][4];
    if ((t & 63) == 0) { red[0][t >> 6] = s; red[1][t >> 6] = s2; }
    __syncthreads();
    s = red[0][0] + red[0][1] + red[0][2] + red[0][3];
    s2 = red[1][0] + red[1][1] + red[1][2] + red[1][3];
    const float mean = s * (1.f / 1024.f);
    const float var = s2 * (1.f / 1024.f) - mean * mean;
    const float rstd = rsqrtf(var + 1e-6f);
    const float4 gv = *(const float4*)(g + t * 4);
    const float4 bv = *(const float4*)(b + t * 4);
    union { bf16_t h4[4]; uint2 u; } o;
    o.h4[0] = (bf16_t)((v.x - mean) * rstd * gv.x + bv.x);
    o.h4[1] = (bf16_t)((v.y - mean) * rstd * gv.y + bv.y);
    o.h4[2] = (bf16_t)((v.z - mean) * rstd * gv.z + bv.z);
    o.h4[3] = (bf16_t)((v.w - mean) * rstd * gv.w + bv.w);
    *(uint2*)(h + (size_t)row * D_ + t * 4) = o.u;
}

// ---------------- fused QKV GEMM; q scaled by 0.125*log2e ----------------
__global__ __launch_bounds__(256) void gemm_qkv(const bf16_t* __restrict__ A,
                                                const bf16_t* __restrict__ BT,
                                                const float* __restrict__ bq,
                                                const float* __restrict__ bk,
                                                const float* __restrict__ bv,
                                                bf16_t* __restrict__ qb,
                                                bf16_t* __restrict__ kb,
                                                bf16_t* __restrict__ vb) {
    constexpr int K = 1024;
    __shared__ bf16_t As[128 * 32];
    __shared__ bf16_t Bs[128 * 32];
    const int t = threadIdx.x;
    const int wave = t >> 6, lane = t & 63;
    const int l16 = lane & 15, g4 = lane >> 4;
    const int bm = blockIdx.x * 128, bn = blockIdx.y * 128;
    const int wm = (wave >> 1) * 64, wn = (wave & 1) * 64;

    f32x4 acc[4][4];
    for (int i = 0; i < 4; ++i)
        for (int j = 0; j < 4; ++j) acc[i][j] = (f32x4){0.f, 0.f, 0.f, 0.f};

    const int ar = t >> 2, ak = (t & 3) * 8;
    const bf16_t* Ag = A + (size_t)(bm + ar) * K + ak;
    const bf16_t* Bg = BT + (size_t)(bn + ar) * K + ak;
    bf16_t* Al = As + t * 8;
    bf16_t* Bl = Bs + t * 8;

    for (int kk = 0; kk < K; kk += 32) {
        __syncthreads();
        gload16(Ag + kk, Al);
        gload16(Ag + (size_t)64 * K + kk, Al + 2048);
        gload16(Bg + kk, Bl);
        gload16(Bg + (size_t)64 * K + kk, Bl + 2048);
        __syncthreads();
        bf16x8 af[4], bfr[4];
        for (int i = 0; i < 4; ++i)
            af[i] = *(const bf16x8*)&As[(wm + i * 16 + l16) * 32 + g4 * 8];
        for (int j = 0; j < 4; ++j)
            bfr[j] = *(const bf16x8*)&Bs[(wn + j * 16 + l16) * 32 + g4 * 8];
        for (int i = 0; i < 4; ++i)
            for (int j = 0; j < 4; ++j)
                acc[i][j] = __builtin_amdgcn_mfma_f32_16x16x32_bf16(af[i], bfr[j], acc[i][j], 0, 0, 0);
    }

    const int which = bn >> 10;             // 0=q, 1=k, 2=v
    const int c0 = bn & 1023;
    const float* bias = (which == 0) ? bq : (which == 1) ? bk : bv;
    bf16_t* ob = (which == 0) ? qb : (which == 1) ? kb : vb;
    const float scale = (which == 0) ? QSCALE : 1.0f;

    for (int i = 0; i < 4; ++i)
        for (int j = 0; j < 4; ++j) {
            const int col = c0 + wn + j * 16 + l16;
            const float bvv = bias[col];
            const int row0 = bm + wm + i * 16 + g4 * 4;
            for (int r = 0; r < 4; ++r) {
                const float vv = (acc[i][j][r] + bvv) * scale;
                ob[(size_t)(row0 + r) * D_ + col] = (bf16_t)vv;
            }
        }
}

// ---------------- GEMM: MODE 1 gelu->bf16, MODE 2 +resid(bf16)->f32 ----------------
template <int MODE>
__global__ __launch_bounds__(256) void gemm_bt(const bf16_t* __restrict__ A,
                                               const bf16_t* __restrict__ BT,
                                               const float* __restrict__ bias,
                                               const bf16_t* __restrict__ residb,
                                               bf16_t* __restrict__ outb,
                                               float* __restrict__ outf) {
    constexpr int K = 1024, N = 1024;
    __shared__ bf16_t As[128 * 32];
    __shared__ bf16_t Bs[128 * 32];
    const int t = threadIdx.x;
    const int wave = t >> 6, lane = t & 63;
    const int l16 = lane & 15, g4 = lane >> 4;
    const int bm = blockIdx.x * 128, bn = blockIdx.y * 128;
    const int wm = (wave >> 1) * 64, wn = (wave & 1) * 64;

    f32x4 acc[4][4];
    for (int i = 0; i < 4; ++i)
        for (int j = 0; j < 4; ++j) acc[i][j] = (f32x4){0.f, 0.f, 0.f, 0.f};

    const int ar = t >> 2, ak = (t & 3) * 8;
    const bf16_t* Ag = A + (size_t)(bm + ar) * K + ak;
    const bf16_t* Bg = BT + (size_t)(bn + ar) * K + ak;
    bf16_t* Al = As + t * 8;
    bf16_t* Bl = Bs + t * 8;

    for (int kk = 0; kk < K; kk += 32) {
        __syncthreads();
        gload16(Ag + kk, Al);
        gload16(Ag + (size_t)64 * K + kk, Al + 2048);
        gload16(Bg + kk, Bl);
        gload16(Bg + (size_t)64 * K + kk, Bl + 2048);
        __syncthreads();
        bf16x8 af[4], bfr[4];
        for (int i = 0; i < 4; ++i)
            af[i] = *(const bf16x8*)&As[(wm + i * 16 + l16) * 32 + g4 * 8];
        for (int j = 0; j < 4; ++j)
            bfr[j] = *(const bf16x8*)&Bs[(wn + j * 16 + l16) * 32 + g4 * 8];
        for (int i = 0; i < 4; ++i)
            for (int j = 0; j < 4; ++j)
                acc[i][j] = __builtin_amdgcn_mfma_f32_16x16x32_bf16(af[i], bfr[j], acc[i][j], 0, 0, 0);
    }

    for (int i = 0; i < 4; ++i)
        for (int j = 0; j < 4; ++j) {
            const int col = bn + wn + j * 16 + l16;
            const float bv = bias[col];
            const int row0 = bm + wm + i * 16 + g4 * 4;
            for (int r = 0; r < 4; ++r) {
                float vv = acc[i][j][r] + bv;
                const size_t idx = (size_t)(row0 + r) * N + col;
                if (MODE == 1) {
                    outb[idx] = (bf16_t)gelu_exact(vv);
                } else {
                    outf[idx] = vv + (float)residb[idx];
                }
            }
        }
}

// ---------------- flash attention v4: gload16+XOR-swizzle K, pre-transposed V ----------------
// 1-D grid of 1024, XCD-swizzled. q pre-scaled by 0.125*log2e; maskbias additive.
#define VT_STRIDE 152
#define OS_STRIDE 72
__global__ __launch_bounds__(256, 3) void attn_kernel(const bf16_t* __restrict__ q,
                                                      const bf16_t* __restrict__ k,
                                                      const bf16_t* __restrict__ vt,
                                                      const float* __restrict__ maskbias,
                                                      bf16_t* __restrict__ attnb) {
    __shared__ bf16_t Ks[128 * 64];              // XOR-swizzled [row][pcg=cg^(row&7)][8]
    __shared__ bf16_t VT[64 * VT_STRIDE];        // padded [d][key]
    bf16_t* Os = VT;                             // epilogue overlay [128][72]

    const int t = threadIdx.x;
    const int wave = t >> 6, lane = t & 63;
    const int l16 = lane & 15, g4 = lane >> 4;
    const int id = blockIdx.x;
    const int xcd = id & 7, seq = id >> 3;
    const int bh = xcd * 8 + (seq >> 4);
    const int b = bh >> 4, h = bh & 15;
    const int q0 = (seq & 15) * 128;

    // Q fragments (B-operand of S^T): lane n=q(l16), holds d = c*32 + g4*8 + j
    bf16x8 qf[2][2];
    for (int ti = 0; ti < 2; ++ti)
        for (int c = 0; c < 2; ++c)
            qf[ti][c] = *(const bf16x8*)(q + (size_t)(b * L_ + q0 + wave * 32 + ti * 16 + l16) * D_ +
                                         h * DH_ + c * 32 + g4 * 8);

    f32x4 accO[2][5];   // [ti][dt]; dt=4 is the ones-row = running row-sum l
    for (int ti = 0; ti < 2; ++ti)
        for (int dt = 0; dt < 5; ++dt) accO[ti][dt] = (f32x4){0.f, 0.f, 0.f, 0.f};

    const bf16_t one_or_zero = (l16 == 0) ? (bf16_t)1.0f : (bf16_t)0.0f;
    const bf16x4 ones4 = (bf16x4){one_or_zero, one_or_zero, one_or_zero, one_or_zero};

    // staging constants (loop-invariant)
    const int krow0 = t >> 3, kcg = t & 7;
    const int klcg = kcg ^ (krow0 & 7);
    const bf16_t* kbase = k + (size_t)(b * L_ + krow0) * D_ + h * DH_ + klcg * 8;
    bf16_t* kdst = Ks + t * 8;
    const int vrow0 = t >> 4, vkg = t & 15;
    const bf16_t* vbase = vt + ((size_t)bh * DH_ + vrow0) * L_ + vkg * 8;
    bf16_t* vdst = &VT[vrow0 * VT_STRIDE + vkg * 8];

    // read bases (loop-invariant, halves)
    const int kb0 = l16 * 64 + ((g4 ^ (l16 & 7)) * 8);
    const int kb1 = l16 * 64 + (((g4 + 4) ^ (l16 & 7)) * 8);
    const int vrb = l16 * VT_STRIDE + g4 * 4;

    for (int k0 = 0; k0 < L_; k0 += 128) {
        __syncthreads();
        #pragma unroll
        for (int it = 0; it < 4; ++it)
            gload16(kbase + (size_t)(k0 + it * 32) * D_, kdst + it * 2048);
        #pragma unroll
        for (int it = 0; it < 4; ++it) {
            const uint4 vv = *(const uint4*)(vbase + (size_t)(it * 16) * L_ + k0);
            *(uint4*)(vdst + it * 16 * VT_STRIDE) = vv;
        }
        __syncthreads();

        // S^T = K Q^T (both ti), C-layout: col=l16=q, row=g4*4+r=key
        f32x4 s0[8], s1[8];
        #pragma unroll
        for (int tj = 0; tj < 8; ++tj) {
            const bf16x8 kf0 = *(const bf16x8*)&Ks[tj * 1024 + kb0];
            const bf16x8 kf1 = *(const bf16x8*)&Ks[tj * 1024 + kb1];
            f32x4 a = (f32x4){0.f, 0.f, 0.f, 0.f};
            a = __builtin_amdgcn_mfma_f32_16x16x32_bf16(kf0, qf[0][0], a, 0, 0, 0);
            a = __builtin_amdgcn_mfma_f32_16x16x32_bf16(kf1, qf[0][1], a, 0, 0, 0);
            s0[tj] = a;
            f32x4 a2 = (f32x4){0.f, 0.f, 0.f, 0.f};
            a2 = __builtin_amdgcn_mfma_f32_16x16x32_bf16(kf0, qf[1][0], a2, 0, 0, 0);
            a2 = __builtin_amdgcn_mfma_f32_16x16x32_bf16(kf1, qf[1][1], a2, 0, 0, 0);
            s1[tj] = a2;
        }

        // p = exp2(s + maskbias); no max-tracking (|s| small, fp32 range huge)
        bf16x4 pb0[8], pb1[8];
        #pragma unroll
        for (int tj = 0; tj < 8; ++tj) {
            const float4 mb = *(const float4*)&maskbias[b * L_ + k0 + tj * 16 + g4 * 4];
            float p00 = fast_exp2(s0[tj][0] + mb.x), p01 = fast_exp2(s0[tj][1] + mb.y);
            float p02 = fast_exp2(s0[tj][2] + mb.z), p03 = fast_exp2(s0[tj][3] + mb.w);
            float p10 = fast_exp2(s1[tj][0] + mb.x), p11 = fast_exp2(s1[tj][1] + mb.y);
            float p12 = fast_exp2(s1[tj][2] + mb.z), p13 = fast_exp2(s1[tj][3] + mb.w);
            pb0[tj] = (bf16x4){(bf16_t)p00, (bf16_t)p01, (bf16_t)p02, (bf16_t)p03};
            pb1[tj] = (bf16x4){(bf16_t)p10, (bf16_t)p11, (bf16_t)p12, (bf16_t)p13};
        }

        // PV: O^T += V^T(A) x P^T(B); dt=4 ones-row accumulates l
        #pragma unroll
        for (int ks = 0; ks < 8; ++ks) {
            #pragma unroll
            for (int dt = 0; dt < 4; ++dt) {
                const bf16x4 va = *(const bf16x4*)&VT[vrb + dt * 16 * VT_STRIDE + ks * 16];
                accO[0][dt] = mfma16(va, pb0[ks], accO[0][dt]);
                accO[1][dt] = mfma16(va, pb1[ks], accO[1][dt]);
            }
            accO[0][4] = mfma16(ones4, pb0[ks], accO[0][4]);
            accO[1][4] = mfma16(ones4, pb1[ks], accO[1][4]);
        }
    }

    // epilogue: normalize by l, transpose via LDS overlay, bf16 out
    __syncthreads();
    for (int ti = 0; ti < 2; ++ti) {
        const float lv = __shfl(accO[ti][4][0], l16, 64);
        const float rl = 1.0f / lv;
        #pragma unroll
        for (int dt = 0; dt < 4; ++dt) {
            bf16x4 o4 = (bf16x4){(bf16_t)(accO[ti][dt][0] * rl), (bf16_t)(accO[ti][dt][1] * rl),
                                 (bf16_t)(accO[ti][dt][2] * rl), (bf16_t)(accO[ti][dt][3] * rl)};
            *(bf16x4*)&Os[(wave * 32 + ti * 16 + l16) * OS_STRIDE + dt * 16 + g4 * 4] = o4;
        }
    }
    __syncthreads();
    for (int cc = 0; cc < 4; ++cc) {
        const int c2 = t + cc * 256;
        const int row = c2 >> 3, k8 = c2 & 7;
        const uint4 vv = *(const uint4*)&Os[row * OS_STRIDE + k8 * 8];
        *(uint4*)&attnb[(size_t)(b * L_ + q0 + row) * D_ + h * DH_ + k8 * 8] = vv;
    }
}

extern "C" void kernel_launch(void* const* d_in, const int* in_sizes, int n_in,
                              void* d_out, int out_size, void* d_ws, size_t ws_size,
                              hipStream_t stream) {
    const float* x    = (const float*)d_in[0];
    const int*   mask = (const int*)d_in[1];
    const float* Wq   = (const float*)d_in[2];
    const float* bq   = (const float*)d_in[3];
    const float* Wk   = (const float*)d_in[4];
    const float* bk   = (const float*)d_in[5];
    const float* Wv   = (const float*)d_in[6];
    const float* bv   = (const float*)d_in[7];
    const float* g1   = (const float*)d_in[8];
    const float* b1   = (const float*)d_in[9];
    const float* g2   = (const float*)d_in[10];
    const float* b2   = (const float*)d_in[11];
    const float* Wo1  = (const float*)d_in[12];
    const float* bo1  = (const float*)d_in[13];
    const float* Wo2  = (const float*)d_in[14];
    const float* bo2  = (const float*)d_in[15];

    char* ws = (char*)d_ws;
    const size_t MBs = 1ull << 20;
    bf16_t* WqkvT = (bf16_t*)(ws + 0 * MBs);          // [3072][1024] bf16
    bf16_t* Wo1T  = (bf16_t*)(ws + 6 * MBs);
    bf16_t* Wo2T  = (bf16_t*)(ws + 8 * MBs);
    bf16_t* h1    = (bf16_t*)(ws + 10 * MBs);         // dead after gemm_qkv
    bf16_t* vtb   = h1;                               // vt overlays h1 (16 MB)
    bf16_t* qb    = (bf16_t*)(ws + 26 * MBs);
    bf16_t* kb    = (bf16_t*)(ws + 42 * MBs);
    bf16_t* vb    = (bf16_t*)(ws + 58 * MBs);
    bf16_t* attnb = (bf16_t*)(ws + 74 * MBs);
    bf16_t* residb= (bf16_t*)(ws + 90 * MBs);
    float*  mbias = (float*)(ws + 106 * MBs);
    bf16_t* h2    = qb;   // reuse
    bf16_t* gact  = kb;   // reuse

    transpose5<<<dim3(32, 32, 5), dim3(32, 8), 0, stream>>>(
        Wq, Wk, Wv, Wo1, Wo2,
        WqkvT, WqkvT + (size_t)D_ * D_, WqkvT + (size_t)2 * D_ * D_, Wo1T, Wo2T);

    maskbias_kernel<<<M_ / 256, 256, 0, stream>>>(mask, mbias);

    ln1_kernel<<<M_, 256, 0, stream>>>(x, g1, b1, h1);

    gemm_qkv<<<dim3(M_ / 128, 3 * D_ / 128), 256, 0, stream>>>(h1, WqkvT, bq, bk, bv, qb, kb, vb);

    vtrans_kernel<<<dim3(L_ / 128, B_ * H_), 256, 0, stream>>>(vb, vtb);

    attn_kernel<<<dim3(1024), 256, 0, stream>>>(qb, kb, vtb, mbias, attnb);

    add_ln2_kernel<<<M_, 256, 0, stream>>>(x, attnb, g2, b2, residb, h2);

    const dim3 gg(M_ / 128, D_ / 128);
    gemm_bt<1><<<gg, 256, 0, stream>>>(h2, Wo1T, bo1, nullptr, gact, nullptr);
    gemm_bt<2><<<gg, 256, 0, stream>>>(gact, Wo2T, bo2, residb, nullptr, (float*)d_out);
}

// Round 5
// 341.085 us; speedup vs baseline: 1.6989x; 1.0993x over previous
//
#include <hip/hip_runtime.h>
#include <stdint.h>
#include <math.h>

typedef __bf16 bf16_t;
typedef __bf16 bf16x8 __attribute__((ext_vector_type(8)));
typedef __bf16 bf16x4 __attribute__((ext_vector_type(4)));
typedef float f32x4 __attribute__((ext_vector_type(4)));

#define B_ 4
#define L_ 2048
#define D_ 1024
#define H_ 16
#define DH_ 64
#define M_ (B_ * L_)   // 8192
#define QSCALE 0.18033688011112042f   // 0.125 * log2(e): softmax in exp2 domain

__device__ __forceinline__ void gload16(const bf16_t* gsrc, bf16_t* ldst) {
    __builtin_amdgcn_global_load_lds(
        (__attribute__((address_space(1))) void*)(void*)(gsrc),
        (__attribute__((address_space(3))) void*)(ldst), 16, 0, 0);
}

__device__ __forceinline__ float gelu_exact(float v) {
    return 0.5f * v * (1.0f + erff(v * 0.70710678118654752f));
}

__device__ __forceinline__ float fast_exp2(float x) {
#if __has_builtin(__builtin_amdgcn_exp2f)
    return __builtin_amdgcn_exp2f(x);
#else
    return exp2f(x);
#endif
}

// ---------------- 5 weight transposes fused: WT[n][k] = W[k][n], fp32 -> bf16 ----------------
__global__ __launch_bounds__(256) void transpose5(const float* __restrict__ W0, const float* __restrict__ W1,
                                                  const float* __restrict__ W2, const float* __restrict__ W3,
                                                  const float* __restrict__ W4,
                                                  bf16_t* __restrict__ T0, bf16_t* __restrict__ T1,
                                                  bf16_t* __restrict__ T2, bf16_t* __restrict__ T3,
                                                  bf16_t* __restrict__ T4) {
    const float* W; bf16_t* T;
    switch (blockIdx.z) {
        case 0: W = W0; T = T0; break;
        case 1: W = W1; T = T1; break;
        case 2: W = W2; T = T2; break;
        case 3: W = W3; T = T3; break;
        default: W = W4; T = T4; break;
    }
    __shared__ float tile[32][33];
    const int x = threadIdx.x, y0 = threadIdx.y;
    const int bx = blockIdx.x * 32, by = blockIdx.y * 32;
    for (int kk = 0; kk < 4; ++kk)
        tile[y0 + kk * 8][x] = W[(size_t)(by + y0 + kk * 8) * D_ + bx + x];
    __syncthreads();
    for (int kk = 0; kk < 4; ++kk)
        T[(size_t)(bx + y0 + kk * 8) * D_ + by + x] = (bf16_t)tile[x][y0 + kk * 8];
}

// ---------------- mask -> additive bias (0 or -1e30) + per-128-chunk all-valid flag ----------------
__global__ __launch_bounds__(256) void maskbias_kernel(const int* __restrict__ mask,
                                                       float* __restrict__ mb,
                                                       unsigned char* __restrict__ flags) {
    const int i = blockIdx.x * 256 + threadIdx.x;
    const int m = mask[i];
    mb[i] = m ? 0.f : -1.0e30f;
    const unsigned long long bal = __ballot(m != 0);
    __shared__ unsigned char ok[4];
    if ((threadIdx.x & 63) == 0) ok[threadIdx.x >> 6] = (bal == ~0ull) ? 1 : 0;
    __syncthreads();
    if (threadIdx.x < 2)
        flags[blockIdx.x * 2 + threadIdx.x] =
            (unsigned char)(ok[threadIdx.x * 2] & ok[threadIdx.x * 2 + 1]);
}

// ---------------- per-head V transpose (key-PERMUTED): vt[b,h,d,pos], pos within 32-chunk ----
// pos = g*8 + b16*4 + r  for actual key = b16*16 + g*4 + r  (matches 16x16x32 B-operand layout)
#define VTR_STRIDE 76
__global__ __launch_bounds__(256) void vtrans_kernel(const bf16_t* __restrict__ vb,
                                                     bf16_t* __restrict__ vt) {
    __shared__ bf16_t tile[128 * VTR_STRIDE];
    const int t = threadIdx.x;
    const int bh = blockIdx.y, b = bh >> 4, h = bh & 15;
    const int k0 = blockIdx.x * 128;
    #pragma unroll
    for (int it = 0; it < 4; ++it) {
        const int row = it * 32 + (t >> 3), c8 = (t & 7) * 8;
        *(uint4*)&tile[row * VTR_STRIDE + c8] =
            *(const uint4*)(vb + (size_t)(b * L_ + k0 + row) * D_ + h * DH_ + c8);
    }
    __syncthreads();
    #pragma unroll
    for (int it = 0; it < 4; ++it) {
        const int d = it * 16 + (t >> 4), pos0 = (t & 15) * 8;
        const int base32 = pos0 & ~31, g = (pos0 >> 3) & 3;
        union { uint4 u; bf16_t e[8]; } tv;
        #pragma unroll
        for (int j = 0; j < 8; ++j) {
            const int kk = base32 + ((j >> 2) << 4) + (g << 2) + (j & 3);
            tv.e[j] = tile[kk * VTR_STRIDE + d];
        }
        *(uint4*)&vt[((size_t)bh * DH_ + d) * L_ + k0 + pos0] = tv.u;
    }
}

// ---------------- LayerNorm 1: x -> h (bf16) ----------------
__global__ __launch_bounds__(256) void ln1_kernel(const float* __restrict__ x,
                                                  const float* __restrict__ g,
                                                  const float* __restrict__ b,
                                                  bf16_t* __restrict__ h) {
    const int row = blockIdx.x, t = threadIdx.x;
    const float4 v = *(const float4*)(x + (size_t)row * D_ + t * 4);
    float s = v.x + v.y + v.z + v.w;
    float s2 = v.x * v.x + v.y * v.y + v.z * v.z + v.w * v.w;
    for (int m = 1; m < 64; m <<= 1) { s += __shfl_xor(s, m, 64); s2 += __shfl_xor(s2, m, 64); }
    __shared__ float red[2][4];
    if ((t & 63) == 0) { red[0][t >> 6] = s; red[1][t >> 6] = s2; }
    __syncthreads();
    s = red[0][0] + red[0][1] + red[0][2] + red[0][3];
    s2 = red[1][0] + red[1][1] + red[1][2] + red[1][3];
    const float mean = s * (1.f / 1024.f);
    const float var = s2 * (1.f / 1024.f) - mean * mean;
    const float rstd = rsqrtf(var + 1e-6f);
    const float4 gv = *(const float4*)(g + t * 4);
    const float4 bv = *(const float4*)(b + t * 4);
    union { bf16_t h4[4]; uint2 u; } o;
    o.h4[0] = (bf16_t)((v.x - mean) * rstd * gv.x + bv.x);
    o.h4[1] = (bf16_t)((v.y - mean) * rstd * gv.y + bv.y);
    o.h4[2] = (bf16_t)((v.z - mean) * rstd * gv.z + bv.z);
    o.h4[3] = (bf16_t)((v.w - mean) * rstd * gv.w + bv.w);
    *(uint2*)(h + (size_t)row * D_ + t * 4) = o.u;
}

// ---------------- residual add (bf16 attn) + LayerNorm 2 -> resid bf16, h bf16 ----------------
__global__ __launch_bounds__(256) void add_ln2_kernel(const float* __restrict__ x,
                                                      const bf16_t* __restrict__ attnb,
                                                      const float* __restrict__ g,
                                                      const float* __restrict__ b,
                                                      bf16_t* __restrict__ residb,
                                                      bf16_t* __restrict__ h) {
    const int row = blockIdx.x, t = threadIdx.x;
    const float4 xv = *(const float4*)(x + (size_t)row * D_ + t * 4);
    union { uint2 u; bf16_t h4[4]; } ai;
    ai.u = *(const uint2*)(attnb + (size_t)row * D_ + t * 4);
    float4 v;
    v.x = xv.x + (float)ai.h4[0]; v.y = xv.y + (float)ai.h4[1];
    v.z = xv.z + (float)ai.h4[2]; v.w = xv.w + (float)ai.h4[3];
    union { bf16_t h4[4]; uint2 u; } rs;
    rs.h4[0] = (bf16_t)v.x; rs.h4[1] = (bf16_t)v.y; rs.h4[2] = (bf16_t)v.z; rs.h4[3] = (bf16_t)v.w;
    *(uint2*)(residb + (size_t)row * D_ + t * 4) = rs.u;
    float s = v.x + v.y + v.z + v.w;
    float s2 = v.x * v.x + v.y * v.y + v.z * v.z + v.w * v.w;
    for (int m = 1; m < 64; m <<= 1) { s += __shfl_xor(s, m, 64); s2 += __shfl_xor(s2, m, 64); }
    __shared__ float red[2][4];
    if ((t & 63) == 0) { red[0][t >> 6] = s; red[1][t >> 6] = s2; }
    __syncthreads();
    s = red[0][0] + red[0][1] + red[0][2] + red[0][3];
    s2 = red[1][0] + red[1][1] + red[1][2] + red[1][3];
    const float mean = s * (1.f / 1024.f);
    const float var = s2 * (1.f / 1024.f) - mean * mean;
    const float rstd = rsqrtf(var + 1e-6f);
    const float4 gv = *(const float4*)(g + t * 4);
    const float4 bv = *(const float4*)(b + t * 4);
    union { bf16_t h4[4]; uint2 u; } o;
    o.h4[0] = (bf16_t)((v.x - mean) * rstd * gv.x + bv.x);
    o.h4[1] = (bf16_t)((v.y - mean) * rstd * gv.y + bv.y);
    o.h4[2] = (bf16_t)((v.z - mean) * rstd * gv.z + bv.z);
    o.h4[3] = (bf16_t)((v.w - mean) * rstd * gv.w + bv.w);
    *(uint2*)(h + (size_t)row * D_ + t * 4) = o.u;
}

// ---------------- fused QKV GEMM; q scaled by 0.125*log2e ----------------
__global__ __launch_bounds__(256) void gemm_qkv(const bf16_t* __restrict__ A,
                                                const bf16_t* __restrict__ BT,
                                                const float* __restrict__ bq,
                                                const float* __restrict__ bk,
                                                const float* __restrict__ bv,
                                                bf16_t* __restrict__ qb,
                                                bf16_t* __restrict__ kb,
                                                bf16_t* __restrict__ vb) {
    constexpr int K = 1024;
    __shared__ bf16_t As[128 * 32];
    __shared__ bf16_t Bs[128 * 32];
    const int t = threadIdx.x;
    const int wave = t >> 6, lane = t & 63;
    const int l16 = lane & 15, g4 = lane >> 4;
    const int bm = blockIdx.x * 128, bn = blockIdx.y * 128;
    const int wm = (wave >> 1) * 64, wn = (wave & 1) * 64;

    f32x4 acc[4][4];
    for (int i = 0; i < 4; ++i)
        for (int j = 0; j < 4; ++j) acc[i][j] = (f32x4){0.f, 0.f, 0.f, 0.f};

    const int ar = t >> 2, ak = (t & 3) * 8;
    const bf16_t* Ag = A + (size_t)(bm + ar) * K + ak;
    const bf16_t* Bg = BT + (size_t)(bn + ar) * K + ak;
    bf16_t* Al = As + t * 8;
    bf16_t* Bl = Bs + t * 8;

    for (int kk = 0; kk < K; kk += 32) {
        __syncthreads();
        gload16(Ag + kk, Al);
        gload16(Ag + (size_t)64 * K + kk, Al + 2048);
        gload16(Bg + kk, Bl);
        gload16(Bg + (size_t)64 * K + kk, Bl + 2048);
        __syncthreads();
        bf16x8 af[4], bfr[4];
        for (int i = 0; i < 4; ++i)
            af[i] = *(const bf16x8*)&As[(wm + i * 16 + l16) * 32 + g4 * 8];
        for (int j = 0; j < 4; ++j)
            bfr[j] = *(const bf16x8*)&Bs[(wn + j * 16 + l16) * 32 + g4 * 8];
        for (int i = 0; i < 4; ++i)
            for (int j = 0; j < 4; ++j)
                acc[i][j] = __builtin_amdgcn_mfma_f32_16x16x32_bf16(af[i], bfr[j], acc[i][j], 0, 0, 0);
    }

    const int which = bn >> 10;             // 0=q, 1=k, 2=v
    const int c0 = bn & 1023;
    const float* bias = (which == 0) ? bq : (which == 1) ? bk : bv;
    bf16_t* ob = (which == 0) ? qb : (which == 1) ? kb : vb;
    const float scale = (which == 0) ? QSCALE : 1.0f;

    for (int i = 0; i < 4; ++i)
        for (int j = 0; j < 4; ++j) {
            const int col = c0 + wn + j * 16 + l16;
            const float bvv = bias[col];
            const int row0 = bm + wm + i * 16 + g4 * 4;
            for (int r = 0; r < 4; ++r) {
                const float vv = (acc[i][j][r] + bvv) * scale;
                ob[(size_t)(row0 + r) * D_ + col] = (bf16_t)vv;
            }
        }
}

// ---------------- GEMM: MODE 1 gelu->bf16, MODE 2 +resid(bf16)->f32 ----------------
template <int MODE>
__global__ __launch_bounds__(256) void gemm_bt(const bf16_t* __restrict__ A,
                                               const bf16_t* __restrict__ BT,
                                               const float* __restrict__ bias,
                                               const bf16_t* __restrict__ residb,
                                               bf16_t* __restrict__ outb,
                                               float* __restrict__ outf) {
    constexpr int K = 1024, N = 1024;
    __shared__ bf16_t As[128 * 32];
    __shared__ bf16_t Bs[128 * 32];
    const int t = threadIdx.x;
    const int wave = t >> 6, lane = t & 63;
    const int l16 = lane & 15, g4 = lane >> 4;
    const int bm = blockIdx.x * 128, bn = blockIdx.y * 128;
    const int wm = (wave >> 1) * 64, wn = (wave & 1) * 64;

    f32x4 acc[4][4];
    for (int i = 0; i < 4; ++i)
        for (int j = 0; j < 4; ++j) acc[i][j] = (f32x4){0.f, 0.f, 0.f, 0.f};

    const int ar = t >> 2, ak = (t & 3) * 8;
    const bf16_t* Ag = A + (size_t)(bm + ar) * K + ak;
    const bf16_t* Bg = BT + (size_t)(bn + ar) * K + ak;
    bf16_t* Al = As + t * 8;
    bf16_t* Bl = Bs + t * 8;

    for (int kk = 0; kk < K; kk += 32) {
        __syncthreads();
        gload16(Ag + kk, Al);
        gload16(Ag + (size_t)64 * K + kk, Al + 2048);
        gload16(Bg + kk, Bl);
        gload16(Bg + (size_t)64 * K + kk, Bl + 2048);
        __syncthreads();
        bf16x8 af[4], bfr[4];
        for (int i = 0; i < 4; ++i)
            af[i] = *(const bf16x8*)&As[(wm + i * 16 + l16) * 32 + g4 * 8];
        for (int j = 0; j < 4; ++j)
            bfr[j] = *(const bf16x8*)&Bs[(wn + j * 16 + l16) * 32 + g4 * 8];
        for (int i = 0; i < 4; ++i)
            for (int j = 0; j < 4; ++j)
                acc[i][j] = __builtin_amdgcn_mfma_f32_16x16x32_bf16(af[i], bfr[j], acc[i][j], 0, 0, 0);
    }

    for (int i = 0; i < 4; ++i)
        for (int j = 0; j < 4; ++j) {
            const int col = bn + wn + j * 16 + l16;
            const float bv = bias[col];
            const int row0 = bm + wm + i * 16 + g4 * 4;
            for (int r = 0; r < 4; ++r) {
                float vv = acc[i][j][r] + bv;
                const size_t idx = (size_t)(row0 + r) * N + col;
                if (MODE == 1) {
                    outb[idx] = (bf16_t)gelu_exact(vv);
                } else {
                    outf[idx] = vv + (float)residb[idx];
                }
            }
        }
}

// ---------------- flash attention v5: PV via 16x16x32 (permuted V), mask fast path ----------------
#define VT_STRIDE 152
#define OS_STRIDE 72
__global__ __launch_bounds__(256, 3) void attn_kernel(const bf16_t* __restrict__ q,
                                                      const bf16_t* __restrict__ k,
                                                      const bf16_t* __restrict__ vt,
                                                      const float* __restrict__ maskbias,
                                                      const unsigned char* __restrict__ mflags,
                                                      bf16_t* __restrict__ attnb) {
    __shared__ bf16_t Ks[128 * 64];              // XOR-swizzled [row][pcg=cg^(row&7)][8]
    __shared__ bf16_t VT[64 * VT_STRIDE];        // [d][key-pos] (key-permuted layout)
    bf16_t* Os = VT;                             // epilogue overlay [128][72]

    const int t = threadIdx.x;
    const int wave = t >> 6, lane = t & 63;
    const int l16 = lane & 15, g4 = lane >> 4;
    const int id = blockIdx.x;
    const int xcd = id & 7, seq = id >> 3;
    const int bh = xcd * 8 + (seq >> 4);
    const int b = bh >> 4, h = bh & 15;
    const int q0 = (seq & 15) * 128;

    // Q fragments (B-operand of S^T): lane n=q(l16), holds d = c*32 + g4*8 + j
    bf16x8 qf[2][2];
    for (int ti = 0; ti < 2; ++ti)
        for (int c = 0; c < 2; ++c)
            qf[ti][c] = *(const bf16x8*)(q + (size_t)(b * L_ + q0 + wave * 32 + ti * 16 + l16) * D_ +
                                         h * DH_ + c * 32 + g4 * 8);

    f32x4 accO[2][5];   // [ti][dt]; dt=4 is the ones-row = running row-sum l
    for (int ti = 0; ti < 2; ++ti)
        for (int dt = 0; dt < 5; ++dt) accO[ti][dt] = (f32x4){0.f, 0.f, 0.f, 0.f};

    const bf16_t ozv = (l16 == 0) ? (bf16_t)1.0f : (bf16_t)0.0f;
    const bf16x8 ones8 = (bf16x8){ozv, ozv, ozv, ozv, ozv, ozv, ozv, ozv};

    // staging constants (loop-invariant)
    const int krow0 = t >> 3, kcg = t & 7;
    const int klcg = kcg ^ (krow0 & 7);
    const bf16_t* kbase = k + (size_t)(b * L_ + krow0) * D_ + h * DH_ + klcg * 8;
    bf16_t* kdst = Ks + t * 8;
    const int vrow0 = t >> 4, vkg = t & 15;
    const bf16_t* vbase = vt + ((size_t)bh * DH_ + vrow0) * L_ + vkg * 8;
    bf16_t* vdst = &VT[vrow0 * VT_STRIDE + vkg * 8];

    // read bases (loop-invariant)
    const int kb0 = l16 * 64 + ((g4 ^ (l16 & 7)) * 8);
    const int kb1 = l16 * 64 + (((g4 + 4) ^ (l16 & 7)) * 8);
    const int vrb = l16 * VT_STRIDE + g4 * 8;
    const unsigned char* flg = mflags + b * 16;

    for (int k0 = 0; k0 < L_; k0 += 128) {
        __syncthreads();
        #pragma unroll
        for (int it = 0; it < 4; ++it)
            gload16(kbase + (size_t)(k0 + it * 32) * D_, kdst + it * 2048);
        #pragma unroll
        for (int it = 0; it < 4; ++it) {
            const uint4 vv = *(const uint4*)(vbase + (size_t)(it * 16) * L_ + k0);
            *(uint4*)(vdst + it * 16 * VT_STRIDE) = vv;
        }
        __syncthreads();

        // S^T = K Q^T (both ti), C-layout: col=l16=q, row=g4*4+r=key
        f32x4 s0[8], s1[8];
        #pragma unroll
        for (int tj = 0; tj < 8; ++tj) {
            const bf16x8 kf0 = *(const bf16x8*)&Ks[tj * 1024 + kb0];
            const bf16x8 kf1 = *(const bf16x8*)&Ks[tj * 1024 + kb1];
            f32x4 a = (f32x4){0.f, 0.f, 0.f, 0.f};
            a = __builtin_amdgcn_mfma_f32_16x16x32_bf16(kf0, qf[0][0], a, 0, 0, 0);
            a = __builtin_amdgcn_mfma_f32_16x16x32_bf16(kf1, qf[0][1], a, 0, 0, 0);
            s0[tj] = a;
            f32x4 a2 = (f32x4){0.f, 0.f, 0.f, 0.f};
            a2 = __builtin_amdgcn_mfma_f32_16x16x32_bf16(kf0, qf[1][0], a2, 0, 0, 0);
            a2 = __builtin_amdgcn_mfma_f32_16x16x32_bf16(kf1, qf[1][1], a2, 0, 0, 0);
            s1[tj] = a2;
        }

        // mask (slow path only when some key in this chunk is masked)
        if (!flg[k0 >> 7]) {
            #pragma unroll
            for (int tj = 0; tj < 8; ++tj) {
                const float4 mb = *(const float4*)&maskbias[b * L_ + k0 + tj * 16 + g4 * 4];
                s0[tj][0] += mb.x; s0[tj][1] += mb.y; s0[tj][2] += mb.z; s0[tj][3] += mb.w;
                s1[tj][0] += mb.x; s1[tj][1] += mb.y; s1[tj][2] += mb.z; s1[tj][3] += mb.w;
            }
        }

        // p = exp2(s); pack per 32-key chunk: pb8 = {s[2c][0..3], s[2c+1][0..3]}
        bf16x8 pb0[4], pb1[4];
        #pragma unroll
        for (int c = 0; c < 4; ++c) {
            pb0[c] = (bf16x8){(bf16_t)fast_exp2(s0[2 * c][0]), (bf16_t)fast_exp2(s0[2 * c][1]),
                              (bf16_t)fast_exp2(s0[2 * c][2]), (bf16_t)fast_exp2(s0[2 * c][3]),
                              (bf16_t)fast_exp2(s0[2 * c + 1][0]), (bf16_t)fast_exp2(s0[2 * c + 1][1]),
                              (bf16_t)fast_exp2(s0[2 * c + 1][2]), (bf16_t)fast_exp2(s0[2 * c + 1][3])};
            pb1[c] = (bf16x8){(bf16_t)fast_exp2(s1[2 * c][0]), (bf16_t)fast_exp2(s1[2 * c][1]),
                              (bf16_t)fast_exp2(s1[2 * c][2]), (bf16_t)fast_exp2(s1[2 * c][3]),
                              (bf16_t)fast_exp2(s1[2 * c + 1][0]), (bf16_t)fast_exp2(s1[2 * c + 1][1]),
                              (bf16_t)fast_exp2(s1[2 * c + 1][2]), (bf16_t)fast_exp2(s1[2 * c + 1][3])};
        }

        // PV: O^T += V^T(A) x P^T(B) via 16x16x32; dt=4 ones-row accumulates l
        #pragma unroll
        for (int c = 0; c < 4; ++c) {
            #pragma unroll
            for (int dt = 0; dt < 4; ++dt) {
                const bf16x8 va = *(const bf16x8*)&VT[vrb + dt * 16 * VT_STRIDE + c * 32];
                accO[0][dt] = __builtin_amdgcn_mfma_f32_16x16x32_bf16(va, pb0[c], accO[0][dt], 0, 0, 0);
                accO[1][dt] = __builtin_amdgcn_mfma_f32_16x16x32_bf16(va, pb1[c], accO[1][dt], 0, 0, 0);
            }
            accO[0][4] = __builtin_amdgcn_mfma_f32_16x16x32_bf16(ones8, pb0[c], accO[0][4], 0, 0, 0);
            accO[1][4] = __builtin_amdgcn_mfma_f32_16x16x32_bf16(ones8, pb1[c], accO[1][4], 0, 0, 0);
        }
    }

    // epilogue: normalize by l, transpose via LDS overlay, bf16 out
    __syncthreads();
    for (int ti = 0; ti < 2; ++ti) {
        const float lv = __shfl(accO[ti][4][0], l16, 64);
        const float rl = 1.0f / lv;
        #pragma unroll
        for (int dt = 0; dt < 4; ++dt) {
            bf16x4 o4 = (bf16x4){(bf16_t)(accO[ti][dt][0] * rl), (bf16_t)(accO[ti][dt][1] * rl),
                                 (bf16_t)(accO[ti][dt][2] * rl), (bf16_t)(accO[ti][dt][3] * rl)};
            *(bf16x4*)&Os[(wave * 32 + ti * 16 + l16) * OS_STRIDE + dt * 16 + g4 * 4] = o4;
        }
    }
    __syncthreads();
    for (int cc = 0; cc < 4; ++cc) {
        const int c2 = t + cc * 256;
        const int row = c2 >> 3, k8 = c2 & 7;
        const uint4 vv = *(const uint4*)&Os[row * OS_STRIDE + k8 * 8];
        *(uint4*)&attnb[(size_t)(b * L_ + q0 + row) * D_ + h * DH_ + k8 * 8] = vv;
    }
}

extern "C" void kernel_launch(void* const* d_in, const int* in_sizes, int n_in,
                              void* d_out, int out_size, void* d_ws, size_t ws_size,
                              hipStream_t stream) {
    const float* x    = (const float*)d_in[0];
    const int*   mask = (const int*)d_in[1];
    const float* Wq   = (const float*)d_in[2];
    const float* bq   = (const float*)d_in[3];
    const float* Wk   = (const float*)d_in[4];
    const float* bk   = (const float*)d_in[5];
    const float* Wv   = (const float*)d_in[6];
    const float* bv   = (const float*)d_in[7];
    const float* g1   = (const float*)d_in[8];
    const float* b1   = (const float*)d_in[9];
    const float* g2   = (const float*)d_in[10];
    const float* b2   = (const float*)d_in[11];
    const float* Wo1  = (const float*)d_in[12];
    const float* bo1  = (const float*)d_in[13];
    const float* Wo2  = (const float*)d_in[14];
    const float* bo2  = (const float*)d_in[15];

    char* ws = (char*)d_ws;
    const size_t MBs = 1ull << 20;
    bf16_t* WqkvT = (bf16_t*)(ws + 0 * MBs);          // [3072][1024] bf16
    bf16_t* Wo1T  = (bf16_t*)(ws + 6 * MBs);
    bf16_t* Wo2T  = (bf16_t*)(ws + 8 * MBs);
    bf16_t* h1    = (bf16_t*)(ws + 10 * MBs);         // dead after gemm_qkv
    bf16_t* vtb   = h1;                               // vt overlays h1 (16 MB)
    bf16_t* qb    = (bf16_t*)(ws + 26 * MBs);
    bf16_t* kb    = (bf16_t*)(ws + 42 * MBs);
    bf16_t* vb    = (bf16_t*)(ws + 58 * MBs);
    bf16_t* attnb = (bf16_t*)(ws + 74 * MBs);
    bf16_t* residb= (bf16_t*)(ws + 90 * MBs);
    float*  mbias = (float*)(ws + 106 * MBs);
    unsigned char* mflags = (unsigned char*)(ws + 107 * MBs);
    bf16_t* h2    = qb;   // reuse
    bf16_t* gact  = kb;   // reuse

    transpose5<<<dim3(32, 32, 5), dim3(32, 8), 0, stream>>>(
        Wq, Wk, Wv, Wo1, Wo2,
        WqkvT, WqkvT + (size_t)D_ * D_, WqkvT + (size_t)2 * D_ * D_, Wo1T, Wo2T);

    maskbias_kernel<<<M_ / 256, 256, 0, stream>>>(mask, mbias, mflags);

    ln1_kernel<<<M_, 256, 0, stream>>>(x, g1, b1, h1);

    gemm_qkv<<<dim3(M_ / 128, 3 * D_ / 128), 256, 0, stream>>>(h1, WqkvT, bq, bk, bv, qb, kb, vb);

    vtrans_kernel<<<dim3(L_ / 128, B_ * H_), 256, 0, stream>>>(vb, vtb);

    attn_kernel<<<dim3(1024), 256, 0, stream>>>(qb, kb, vtb, mbias, mflags, attnb);

    add_ln2_kernel<<<M_, 256, 0, stream>>>(x, attnb, g2, b2, residb, h2);

    const dim3 gg(M_ / 128, D_ / 128);
    gemm_bt<1><<<gg, 256, 0, stream>>>(h2, Wo1T, bo1, nullptr, gact, nullptr);
    gemm_bt<2><<<gg, 256, 0, stream>>>(gact, Wo2T, bo2, residb, nullptr, (float*)d_out);
}